// Round 2
// baseline (1370.587 us; speedup 1.0000x reference)
//
#include <hip/hip_runtime.h>
#include <hip/hip_bf16.h>

#define RR 4096
#define AA 101
#define KK 32
#define NAG 4000000

static constexpr float EPS  = 1e-9f;
static constexpr float DT   = 1.0f / 365.0f;
static constexpr float FRAC_MOVE = 0.02f / 365.0f;   // RATE_ANN*dt, within [0,0.25]

// ---------------- d_out offsets (f32 elements, return order) ----------------
#define OUT_POP   0
#define OUT_POPN  413696
#define OUT_GDP   417792
#define OUT_DEV   421888
#define OUT_H     425984
#define OUT_CONS  430080
#define OUT_LAB   434176
#define OUT_PSR   438272
#define OUT_DEP   442368
#define OUT_ATP   446464
#define OUT_ADP   4446464
#define OUT_AMP   8446464
#define OUT_PATP  12446464
#define OUT_PADP  12450560
#define OUT_PAMP  12454656

static __device__ __forceinline__ float clampf(float x, float lo, float hi) {
    return fminf(fmaxf(x, lo), hi);
}

// ---------------- kernel: zero the accumulator region ----------------
__global__ void k_zero(float* __restrict__ p, int n) {
    int i = blockIdx.x * blockDim.x + threadIdx.x;
    if (i < n) p[i] = 0.0f;
}

// ---------------- kernel 1: per-region stage 1 ----------------
__global__ __launch_bounds__(256) void k_region1(
    const float* __restrict__ aec, const float* __restrict__ gdp_pc,
    const float* __restrict__ gdp_ema_in, const float* __restrict__ gdp_base,
    const float* __restrict__ dev_in, const float* __restrict__ sink_use,
    const float* __restrict__ sink_cap, const float* __restrict__ haz_base,
    const float* __restrict__ pop_age, const float* __restrict__ population,
    const float* __restrict__ aging, const float* __restrict__ asfr,
    const float* __restrict__ distance, const int* __restrict__ nbr,
    float* __restrict__ Wpa, float* __restrict__ Wdfrac, float* __restrict__ Wbsurv,
    float* __restrict__ Wattr, float* __restrict__ Wgdist, float* __restrict__ Wscal,
    float* __restrict__ out_gdp, float* __restrict__ out_dev,
    float* __restrict__ out_H)
{
    int r = blockIdx.x * blockDim.x + threadIdx.x;
    if (r >= RR) return;

    float aec_norm = clampf(aec[r], 0.0f, 1.0f);
    float gprev = gdp_ema_in[r];
    float gema  = gprev * 0.9f + 0.1f * gdp_pc[r];
    float base  = gdp_base[r];
    float g_ratio = logf(fmaxf(gema / (base + EPS), 1e-6f));
    float g_term  = clampf(0.5f + 0.5f * tanhf(0.5f * g_ratio), 0.0f, 1.0f);
    float util = clampf(sink_use[r] / (sink_cap[r] + EPS), 0.0f, 1.0f);
    float H = clampf(0.5f * aec_norm + 0.4f * g_term + 0.1f * (1.0f - util), 0.0f, 1.0f);
    float dev_proxy = clampf(0.5f + 0.5f * tanhf(0.3f * g_ratio), 0.0f, 1.0f);
    float dev = dev_in[r] * 0.99f + 0.01f * dev_proxy;

    out_gdp[r] = gema;
    out_dev[r] = dev;
    out_H[r]   = H;

    float m_neon  = expf(-2.0f * H);
    float m_child = expf(-1.5f * H);
    float m_adult = expf(-1.0f * H);
    float hazmul = 1.0f + 0.5f * util;

    float pop_sum = 0.f, surv_sum = 0.f, haz05 = 0.f, haz0 = 0.f;
    float b_sum = 0.f, surv_prev = 0.f, pa0 = 0.f;

    for (int a = 0; a < AA; a++) {
        float mult = (a == 0) ? m_neon : ((a < 15) ? m_child : m_adult);
        float hz = clampf(haz_base[a] * mult * hazmul, 0.0f, 5.0f);
        float p = pop_age[r * AA + a];
        float s = p * expf(-hz * DT);
        pop_sum += p;
        surv_sum += s;
        if (a < 5) haz05 += hz;
        if (a == 0) haz0 = hz;
        float Md = aging[a * AA + a];
        float pa;
        if (a == 0) {
            pa = s * Md;
            pa0 = pa;
        } else {
            float Ms = aging[(a - 1) * AA + a];
            pa = s * Md + surv_prev * Ms;
            Wpa[r * AA + a] = pa;
        }
        surv_prev = s;
        if (a >= 15 && a < 50) b_sum += 0.5f * pa * asfr[a - 15];
    }

    float deaths = fmaxf(pop_sum - surv_sum, 0.0f);
    float dfrac = clampf(deaths / (population[r] + EPS), 0.0f, 0.99f);
    Wdfrac[r] = dfrac;

    float surv_u5 = expf(-haz05);
    float F_dev = clampf(expf(-dev), 0.5f, 1.5f);                     // THETA_DEV=1
    float F_rep = clampf(0.995f / fmaxf(surv_u5, 0.001f), 0.5f, 1.8f); // PHI_REP=1
    float g_growth = logf(fmaxf(gema + EPS, 1e-6f)) - logf(fmaxf(gprev + EPS, 1e-6f));
    float F_cyc = clampf(expf(-5.0f * fmaxf(-g_growth, 0.0f)), 0.6f, 1.2f);
    float F_total = clampf(F_dev * F_rep * F_cyc, 0.4f, 1.8f);
    float births = fmaxf(b_sum * F_total * DT, 0.0f);
    float bsurv = births * expf(-haz0 * DT);
    Wbsurv[r] = bsurv;
    Wpa[r * AA + 0] = pa0 + bsurv;

    float attr = 0.6f * (gdp_pc[r] / (base + EPS)) + 0.4f * (0.5f + 0.5f * aec_norm);
    Wattr[r] = attr;
    atomicAdd(&Wscal[0], attr);

    float dsum = 0.f;
    for (int k = 0; k < KK; k++) {
        int idx = nbr[r * KK + k];
        float d = distance[(size_t)r * RR + idx];
        Wgdist[r * KK + k] = d;
        dsum += d;
    }
    atomicAdd(&Wscal[1], dsum);
}

// ---------------- kernel 2a: migration weights + outflow ----------------
__global__ __launch_bounds__(256) void k_migrate_a(
    const int* __restrict__ nbr, const float* __restrict__ Wattr,
    const float* __restrict__ Wgdist, const float* __restrict__ Wscal,
    float* __restrict__ Wpa, float* __restrict__ Wash, float* __restrict__ Wmove)
{
    int r = blockIdx.x * blockDim.x + threadIdx.x;
    if (r >= RR) return;

    float amean = Wscal[0] / (float)RR;
    float dmean = Wscal[1] / (float)(RR * KK);
    float inv_am = 1.0f / (amean + EPS);
    float inv_dm = 1.0f / (dmean + EPS);

    float mobile[22];
    float msum = 0.f;
#pragma unroll
    for (int f = 0; f < 22; f++) {
        mobile[f] = Wpa[r * AA + 18 + f];
        msum += mobile[f];
    }

    float wv[KK];
    float wsum = 0.f;
#pragma unroll
    for (int k = 0; k < KK; k++) {
        int idx = nbr[r * KK + k];
        float an = Wattr[idx] * inv_am;
        float cost = 1.0f + Wgdist[r * KK + k] * inv_dm;
        float w = fmaxf(an / cost, 0.0f);
        wv[k] = w;
        wsum += w;
    }

    float out_R = msum * FRAC_MOVE;
    float invw = 1.0f / (wsum + EPS);
    float move_sum = out_R * wsum * invw;   // out_R * sum(w_norm)
    float inv_ms = 1.0f / (msum + EPS);

#pragma unroll
    for (int f = 0; f < 22; f++) {
        float ash = mobile[f] * inv_ms;
        Wash[r * 22 + f] = ash;
        Wpa[r * AA + 18 + f] = mobile[f] - ash * move_sum;
    }
#pragma unroll
    for (int k = 0; k < KK; k++) {
        Wmove[r * KK + k] = out_R * wv[k] * invw;
    }
}

// ---------------- kernel 2b: inflow scatter ----------------
__global__ __launch_bounds__(256) void k_migrate_b(
    const int* __restrict__ nbr, const float* __restrict__ Wash,
    const float* __restrict__ Wmove, float* __restrict__ Wadd)
{
    int t = blockIdx.x * blockDim.x + threadIdx.x;   // over R*K
    if (t >= RR * KK) return;
    int r = t >> 5;            // K=32
    int idx = nbr[t];
    float mv = Wmove[t];
    const float* ash = &Wash[r * 22];
    float* dst = &Wadd[idx * 22];
#pragma unroll
    for (int f = 0; f < 22; f++) {
        atomicAdd(&dst[f], ash[f] * mv);
    }
}

// ---------------- kernel 3: finalize population + region stats ----------------
__global__ __launch_bounds__(256) void k_finalize(
    const float* __restrict__ Wpa, const float* __restrict__ Wadd,
    const float* __restrict__ cw, const float* __restrict__ pw,
    const float* __restrict__ cbase, const float* __restrict__ lbase,
    float* __restrict__ O)
{
    int r = blockIdx.x * blockDim.x + threadIdx.x;
    if (r >= RR) return;

    float psum = 0.f, cdot = 0.f, ldot = 0.f, work = 0.f, young = 0.f, old = 0.f;
    for (int a = 0; a < AA; a++) {
        float v = Wpa[r * AA + a];
        if (a >= 18 && a < 40) v += Wadd[r * 22 + (a - 18)];
        v = fmaxf(v, 0.0f);
        O[OUT_POP + r * AA + a] = v;
        psum += v;
        cdot += v * cw[a];
        ldot += v * pw[a];
        if (a < 15) young += v;
        else if (a < 65) work += v;
        else old += v;
    }
    O[OUT_POPN + r] = fmaxf(psum, 0.0f);
    O[OUT_CONS + r] = clampf(cdot / (cbase[r] + EPS), 0.25f, 4.0f);
    O[OUT_LAB + r]  = clampf(ldot / (lbase[r] + EPS), 0.2f, 1.2f);
    O[OUT_PSR + r]  = work / (old + EPS);
    O[OUT_DEP + r]  = (young + old) / (work + EPS);
}

// ---------------- kernel 4: agent segment sums ----------------
__global__ __launch_bounds__(256) void k_agent_sum(
    const int* __restrict__ reg, const float* __restrict__ greed,
    const float* __restrict__ atp, const float* __restrict__ adp,
    const float* __restrict__ amp,
    float* __restrict__ Wsg, float* __restrict__ Wsa, float* __restrict__ Wsd,
    float* __restrict__ Wsm, float* __restrict__ Wsc)
{
    int i = blockIdx.x * blockDim.x + threadIdx.x;
    if (i >= NAG) return;
    int r = reg[i];
    atomicAdd(&Wsg[r], greed[i] + 1e-9f);
    atomicAdd(&Wsa[r], atp[i]);
    atomicAdd(&Wsd[r], adp[i]);
    atomicAdd(&Wsm[r], amp[i]);
    atomicAdd(&Wsc[r], 1.0f);
}

// ---------------- kernel 4b: per-region heir pools / pool outputs ----------------
__global__ __launch_bounds__(256) void k_region2(
    const float* __restrict__ Wsa, const float* __restrict__ Wsd,
    const float* __restrict__ Wsm, const float* __restrict__ Wsc,
    const float* __restrict__ Wdfrac, const float* __restrict__ Wbsurv,
    const float* __restrict__ patp, const float* __restrict__ padp,
    const float* __restrict__ pamp,
    float* __restrict__ WheirA, float* __restrict__ WheirD,
    float* __restrict__ WheirM, float* __restrict__ Wendow,
    float* __restrict__ O)
{
    int r = blockIdx.x * blockDim.x + threadIdx.x;
    if (r >= RR) return;
    float dfi = Wdfrac[r];
    float ra = Wsa[r] * dfi;
    float rd = Wsd[r] * dfi;
    float rm = Wsm[r] * dfi;
    WheirA[r] = ra * 0.8f;                     // INHERIT_FRAC
    WheirD[r] = rd * 0.8f;
    WheirM[r] = rm * 0.8f;
    O[OUT_PATP + r] = patp[r] - ra * 0.2f;     // pool - (removed - heir)
    O[OUT_PADP + r] = padp[r] - rd * 0.2f;
    O[OUT_PAMP + r] = pamp[r] - rm * 0.2f;
    Wendow[r] = Wbsurv[r] / fmaxf(Wsc[r], 1.0f);   // BIRTH_ENDOW=1
}

// ---------------- kernel 5: agent apply ----------------
__global__ __launch_bounds__(256) void k_agent_apply(
    const int* __restrict__ reg, const float* __restrict__ greed,
    const float* __restrict__ atp, const float* __restrict__ adp,
    const float* __restrict__ amp,
    const float* __restrict__ Wsg, const float* __restrict__ Wdfrac,
    const float* __restrict__ WheirA, const float* __restrict__ WheirD,
    const float* __restrict__ WheirM, const float* __restrict__ Wendow,
    float* __restrict__ O)
{
    int i = blockIdx.x * blockDim.x + threadIdx.x;
    if (i >= NAG) return;
    int r = reg[i];
    float dfi = Wdfrac[r];
    float keep = 1.0f - dfi;
    float wn = (greed[i] + 1e-9f) / (Wsg[r] + EPS);
    O[OUT_ATP + i] = atp[i] * keep + wn * WheirA[r] + Wendow[r];
    O[OUT_ADP + i] = adp[i] * keep + wn * WheirD[r];
    O[OUT_AMP + i] = amp[i] * keep + wn * WheirM[r];
}

extern "C" void kernel_launch(void* const* d_in, const int* in_sizes, int n_in,
                              void* d_out, int out_size, void* d_ws, size_t ws_size,
                              hipStream_t stream) {
    const float* aec       = (const float*)d_in[0];
    const float* gdp_pc    = (const float*)d_in[1];
    const float* gdp_ema   = (const float*)d_in[2];
    const float* gdp_base  = (const float*)d_in[3];
    const float* dev_in    = (const float*)d_in[4];
    const float* sink_use  = (const float*)d_in[5];
    const float* sink_cap  = (const float*)d_in[6];
    const float* haz_base  = (const float*)d_in[7];
    const float* pop_age   = (const float*)d_in[8];
    const float* population= (const float*)d_in[9];
    const float* aging     = (const float*)d_in[10];
    const float* asfr      = (const float*)d_in[11];
    const float* distance  = (const float*)d_in[12];
    const float* cw        = (const float*)d_in[13];
    const float* pw        = (const float*)d_in[14];
    const float* cbase     = (const float*)d_in[15];
    const float* lbase     = (const float*)d_in[16];
    const float* greed     = (const float*)d_in[17];
    const float* eATP      = (const float*)d_in[18];
    const float* eADP      = (const float*)d_in[19];
    const float* eAMP      = (const float*)d_in[20];
    const float* patp      = (const float*)d_in[21];
    const float* padp      = (const float*)d_in[22];
    const float* pamp      = (const float*)d_in[23];
    const int*   nbr       = (const int*)d_in[24];
    const int*   reg       = (const int*)d_in[25];

    float* O = (float*)d_out;

    // -------- workspace layout (f32) --------
    float* W = (float*)d_ws;
    float* Wpa    = W;                    // R*A      = 413696
    float* Wdfrac = Wpa    + RR * AA;     // R
    float* Wbsurv = Wdfrac + RR;          // R
    float* Wattr  = Wbsurv + RR;          // R
    float* Wgdist = Wattr  + RR;          // R*K      = 131072
    float* Wash   = Wgdist + RR * KK;     // R*22     = 90112
    float* Wmove  = Wash   + RR * 22;     // R*K
    // ---- zeroed region ----
    float* Wadd   = Wmove  + RR * KK;     // R*22
    float* Wsg    = Wadd   + RR * 22;     // R
    float* Wsa    = Wsg + RR;
    float* Wsd    = Wsa + RR;
    float* Wsm    = Wsd + RR;
    float* Wsc    = Wsm + RR;
    float* Wscal  = Wsc + RR;             // 2
    // ---- end zeroed region ----
    float* WheirA = Wscal + 2;
    float* WheirD = WheirA + RR;
    float* WheirM = WheirD + RR;
    float* Wendow = WheirM + RR;

    const int nzero = RR * 22 + 5 * RR + 2;   // 110594

    k_zero<<<(nzero + 255) / 256, 256, 0, stream>>>(Wadd, nzero);

    k_region1<<<RR / 256, 256, 0, stream>>>(
        aec, gdp_pc, gdp_ema, gdp_base, dev_in, sink_use, sink_cap, haz_base,
        pop_age, population, aging, asfr, distance, nbr,
        Wpa, Wdfrac, Wbsurv, Wattr, Wgdist, Wscal,
        O + OUT_GDP, O + OUT_DEV, O + OUT_H);

    k_migrate_a<<<RR / 256, 256, 0, stream>>>(nbr, Wattr, Wgdist, Wscal, Wpa, Wash, Wmove);

    k_migrate_b<<<(RR * KK) / 256, 256, 0, stream>>>(nbr, Wash, Wmove, Wadd);

    k_finalize<<<RR / 256, 256, 0, stream>>>(Wpa, Wadd, cw, pw, cbase, lbase, O);

    k_agent_sum<<<NAG / 256, 256, 0, stream>>>(reg, greed, eATP, eADP, eAMP,
                                               Wsg, Wsa, Wsd, Wsm, Wsc);

    k_region2<<<RR / 256, 256, 0, stream>>>(Wsa, Wsd, Wsm, Wsc, Wdfrac, Wbsurv,
                                            patp, padp, pamp,
                                            WheirA, WheirD, WheirM, Wendow, O);

    k_agent_apply<<<NAG / 256, 256, 0, stream>>>(reg, greed, eATP, eADP, eAMP,
                                                 Wsg, Wdfrac,
                                                 WheirA, WheirD, WheirM, Wendow, O);
}

// Round 3
// 379.179 us; speedup vs baseline: 3.6146x; 3.6146x over previous
//
#include <hip/hip_runtime.h>
#include <hip/hip_bf16.h>

#define RR 4096
#define AA 101
#define KK 32
#define NAG 4000000

#define HB 128          // histogram partial slices per sum-group
#define DR 512          // dest regions per migrate range-block
#define NRANGE 8        // RR / DR
#define NCHUNK 16       // edge chunks
#define EPB (RR * KK / NCHUNK)   // 8192 edges per chunk

static constexpr float EPS  = 1e-9f;
static constexpr float DT   = 1.0f / 365.0f;
static constexpr float FRAC_MOVE = 0.02f / 365.0f;   // RATE_ANN*dt, within [0,0.25]

// ---------------- d_out offsets (f32 elements, return order) ----------------
#define OUT_POP   0
#define OUT_POPN  413696
#define OUT_GDP   417792
#define OUT_DEV   421888
#define OUT_H     425984
#define OUT_CONS  430080
#define OUT_LAB   434176
#define OUT_PSR   438272
#define OUT_DEP   442368
#define OUT_ATP   446464
#define OUT_ADP   4446464
#define OUT_AMP   8446464
#define OUT_PATP  12446464
#define OUT_PADP  12450560
#define OUT_PAMP  12454656

static __device__ __forceinline__ float clampf(float x, float lo, float hi) {
    return fminf(fmaxf(x, lo), hi);
}

// ---------------- kernel: zero tiny accumulators ----------------
__global__ void k_zero(float* __restrict__ p, int n) {
    int i = blockIdx.x * blockDim.x + threadIdx.x;
    if (i < n) p[i] = 0.0f;
}

// ---------------- kernel 1: per-region stage 1 ----------------
__global__ __launch_bounds__(256) void k_region1(
    const float* __restrict__ aec, const float* __restrict__ gdp_pc,
    const float* __restrict__ gdp_ema_in, const float* __restrict__ gdp_base,
    const float* __restrict__ dev_in, const float* __restrict__ sink_use,
    const float* __restrict__ sink_cap, const float* __restrict__ haz_base,
    const float* __restrict__ pop_age, const float* __restrict__ population,
    const float* __restrict__ aging, const float* __restrict__ asfr,
    const float* __restrict__ distance, const int* __restrict__ nbr,
    float* __restrict__ Wpa, float* __restrict__ Wdfrac, float* __restrict__ Wbsurv,
    float* __restrict__ Wattr, float* __restrict__ Wgdist, float* __restrict__ Wscal,
    float* __restrict__ out_gdp, float* __restrict__ out_dev,
    float* __restrict__ out_H)
{
    int r = blockIdx.x * blockDim.x + threadIdx.x;
    if (r >= RR) return;

    float aec_norm = clampf(aec[r], 0.0f, 1.0f);
    float gprev = gdp_ema_in[r];
    float gema  = gprev * 0.9f + 0.1f * gdp_pc[r];
    float base  = gdp_base[r];
    float g_ratio = logf(fmaxf(gema / (base + EPS), 1e-6f));
    float g_term  = clampf(0.5f + 0.5f * tanhf(0.5f * g_ratio), 0.0f, 1.0f);
    float util = clampf(sink_use[r] / (sink_cap[r] + EPS), 0.0f, 1.0f);
    float H = clampf(0.5f * aec_norm + 0.4f * g_term + 0.1f * (1.0f - util), 0.0f, 1.0f);
    float dev_proxy = clampf(0.5f + 0.5f * tanhf(0.3f * g_ratio), 0.0f, 1.0f);
    float dev = dev_in[r] * 0.99f + 0.01f * dev_proxy;

    out_gdp[r] = gema;
    out_dev[r] = dev;
    out_H[r]   = H;

    float m_neon  = expf(-2.0f * H);
    float m_child = expf(-1.5f * H);
    float m_adult = expf(-1.0f * H);
    float hazmul = 1.0f + 0.5f * util;

    float pop_sum = 0.f, surv_sum = 0.f, haz05 = 0.f, haz0 = 0.f;
    float b_sum = 0.f, surv_prev = 0.f, pa0 = 0.f;

    for (int a = 0; a < AA; a++) {
        float mult = (a == 0) ? m_neon : ((a < 15) ? m_child : m_adult);
        float hz = clampf(haz_base[a] * mult * hazmul, 0.0f, 5.0f);
        float p = pop_age[r * AA + a];
        float s = p * expf(-hz * DT);
        pop_sum += p;
        surv_sum += s;
        if (a < 5) haz05 += hz;
        if (a == 0) haz0 = hz;
        float Md = aging[a * AA + a];
        float pa;
        if (a == 0) {
            pa = s * Md;
            pa0 = pa;
        } else {
            float Ms = aging[(a - 1) * AA + a];
            pa = s * Md + surv_prev * Ms;
            Wpa[r * AA + a] = pa;
        }
        surv_prev = s;
        if (a >= 15 && a < 50) b_sum += 0.5f * pa * asfr[a - 15];
    }

    float deaths = fmaxf(pop_sum - surv_sum, 0.0f);
    float dfrac = clampf(deaths / (population[r] + EPS), 0.0f, 0.99f);
    Wdfrac[r] = dfrac;

    float surv_u5 = expf(-haz05);
    float F_dev = clampf(expf(-dev), 0.5f, 1.5f);                      // THETA_DEV=1
    float F_rep = clampf(0.995f / fmaxf(surv_u5, 0.001f), 0.5f, 1.8f); // PHI_REP=1
    float g_growth = logf(fmaxf(gema + EPS, 1e-6f)) - logf(fmaxf(gprev + EPS, 1e-6f));
    float F_cyc = clampf(expf(-5.0f * fmaxf(-g_growth, 0.0f)), 0.6f, 1.2f);
    float F_total = clampf(F_dev * F_rep * F_cyc, 0.4f, 1.8f);
    float births = fmaxf(b_sum * F_total * DT, 0.0f);
    float bsurv = births * expf(-haz0 * DT);
    Wbsurv[r] = bsurv;
    Wpa[r * AA + 0] = pa0 + bsurv;

    float attr = 0.6f * (gdp_pc[r] / (base + EPS)) + 0.4f * (0.5f + 0.5f * aec_norm);
    Wattr[r] = attr;
    atomicAdd(&Wscal[0], attr);

    float dsum = 0.f;
    for (int k = 0; k < KK; k++) {
        int idx = nbr[r * KK + k];
        float d = distance[(size_t)r * RR + idx];
        Wgdist[r * KK + k] = d;
        dsum += d;
    }
    atomicAdd(&Wscal[1], dsum);
}

// ---------------- kernel 2a: migration weights + outflow ----------------
__global__ __launch_bounds__(256) void k_migrate_a(
    const int* __restrict__ nbr, const float* __restrict__ Wattr,
    const float* __restrict__ Wgdist, const float* __restrict__ Wscal,
    float* __restrict__ Wpa, float* __restrict__ Wash, float* __restrict__ Wmove)
{
    int r = blockIdx.x * blockDim.x + threadIdx.x;
    if (r >= RR) return;

    float amean = Wscal[0] / (float)RR;
    float dmean = Wscal[1] / (float)(RR * KK);
    float inv_am = 1.0f / (amean + EPS);
    float inv_dm = 1.0f / (dmean + EPS);

    float mobile[22];
    float msum = 0.f;
#pragma unroll
    for (int f = 0; f < 22; f++) {
        mobile[f] = Wpa[r * AA + 18 + f];
        msum += mobile[f];
    }

    float wv[KK];
    float wsum = 0.f;
#pragma unroll
    for (int k = 0; k < KK; k++) {
        int idx = nbr[r * KK + k];
        float an = Wattr[idx] * inv_am;
        float cost = 1.0f + Wgdist[r * KK + k] * inv_dm;
        float w = fmaxf(an / cost, 0.0f);
        wv[k] = w;
        wsum += w;
    }

    float out_R = msum * FRAC_MOVE;
    float invw = 1.0f / (wsum + EPS);
    float move_sum = out_R * wsum * invw;   // out_R * sum(w_norm)
    float inv_ms = 1.0f / (msum + EPS);

#pragma unroll
    for (int f = 0; f < 22; f++) {
        float ash = mobile[f] * inv_ms;
        Wash[r * 22 + f] = ash;
        Wpa[r * AA + 18 + f] = mobile[f] - ash * move_sum;
    }
#pragma unroll
    for (int k = 0; k < KK; k++) {
        Wmove[r * KK + k] = out_R * wv[k] * invw;
    }
}

// ---------------- kernel 2b: inflow scatter, LDS range-split, atomic-free ----------------
// grid = NRANGE * NCHUNK blocks; block handles dest range [d0,d0+DR) over edge chunk.
// LDS layout h[f][d] so flush + finalize reads are coalesced.
// Smig layout: [(chunk*22 + f) * RR + d]
__global__ __launch_bounds__(256) void k_migrate_b(
    const int* __restrict__ nbr, const float* __restrict__ Wash,
    const float* __restrict__ Wmove, float* __restrict__ Smig)
{
    __shared__ float h[22 * DR];   // 45056 B
    int range = blockIdx.x & (NRANGE - 1);
    int chunk = blockIdx.x >> 3;
    int d0 = range * DR;

    for (int i = threadIdx.x; i < 22 * DR; i += 256) h[i] = 0.0f;
    __syncthreads();

    int tend = (chunk + 1) * EPB;
    for (int t = chunk * EPB + threadIdx.x; t < tend; t += 256) {
        int idx = nbr[t];
        if (idx >= d0 && idx < d0 + DR) {
            int r = t >> 5;                 // K=32
            float mv = Wmove[t];
            const float* ash = &Wash[r * 22];
            int dl = idx - d0;
#pragma unroll
            for (int f = 0; f < 22; f++) {
                atomicAdd(&h[f * DR + dl], ash[f] * mv);
            }
        }
    }
    __syncthreads();

    for (int i = threadIdx.x; i < 22 * DR; i += 256) {
        int f = i / DR;
        int d = i - f * DR;
        Smig[(chunk * 22 + f) * RR + d0 + d] = h[i];
    }
}

// ---------------- kernel 3: finalize population + region stats ----------------
__global__ __launch_bounds__(256) void k_finalize(
    const float* __restrict__ Wpa, const float* __restrict__ Smig,
    const float* __restrict__ cw, const float* __restrict__ pw,
    const float* __restrict__ cbase, const float* __restrict__ lbase,
    float* __restrict__ O)
{
    int r = blockIdx.x * blockDim.x + threadIdx.x;
    if (r >= RR) return;

    float psum = 0.f, cdot = 0.f, ldot = 0.f, work = 0.f, young = 0.f, old = 0.f;
    for (int a = 0; a < AA; a++) {
        float v = Wpa[r * AA + a];
        if (a >= 18 && a < 40) {
            int f = a - 18;
            float add = 0.f;
#pragma unroll
            for (int c = 0; c < NCHUNK; c++)
                add += Smig[(c * 22 + f) * RR + r];
            v += add;
        }
        v = fmaxf(v, 0.0f);
        O[OUT_POP + r * AA + a] = v;
        psum += v;
        cdot += v * cw[a];
        ldot += v * pw[a];
        if (a < 15) young += v;
        else if (a < 65) work += v;
        else old += v;
    }
    O[OUT_POPN + r] = fmaxf(psum, 0.0f);
    O[OUT_CONS + r] = clampf(cdot / (cbase[r] + EPS), 0.25f, 4.0f);
    O[OUT_LAB + r]  = clampf(ldot / (lbase[r] + EPS), 0.2f, 1.2f);
    O[OUT_PSR + r]  = work / (old + EPS);
    O[OUT_DEP + r]  = (young + old) / (work + EPS);
}

// ---------------- kernel 4: agent segment sums via LDS histograms ----------------
// blocks [0,HB): {atp,adp,amp} -> S3[bid][3][RR]
// blocks [HB,2*HB): {greed,count} -> S2[bid-HB][2][RR]
__global__ __launch_bounds__(256) void k_hist(
    const int* __restrict__ reg, const float* __restrict__ greed,
    const float* __restrict__ atp, const float* __restrict__ adp,
    const float* __restrict__ amp,
    float* __restrict__ S3, float* __restrict__ S2)
{
    __shared__ float h[3 * RR];   // 48 KiB
    int bid = blockIdx.x;
    if (bid < HB) {
        for (int i = threadIdx.x; i < 3 * RR; i += 256) h[i] = 0.0f;
        __syncthreads();
        for (int i = bid * 256 + threadIdx.x; i < NAG; i += HB * 256) {
            int r = reg[i];
            atomicAdd(&h[r],          atp[i]);
            atomicAdd(&h[RR + r],     adp[i]);
            atomicAdd(&h[2 * RR + r], amp[i]);
        }
        __syncthreads();
        for (int i = threadIdx.x; i < 3 * RR; i += 256)
            S3[bid * 3 * RR + i] = h[i];
    } else {
        int b = bid - HB;
        for (int i = threadIdx.x; i < 2 * RR; i += 256) h[i] = 0.0f;
        __syncthreads();
        for (int i = b * 256 + threadIdx.x; i < NAG; i += HB * 256) {
            int r = reg[i];
            atomicAdd(&h[r],      greed[i] + 1e-9f);
            atomicAdd(&h[RR + r], 1.0f);
        }
        __syncthreads();
        for (int i = threadIdx.x; i < 2 * RR; i += 256)
            S2[b * 2 * RR + i] = h[i];
    }
}

// ---------------- kernel 4b: reduce partials + heir pools / pool outputs ----------------
__global__ __launch_bounds__(256) void k_region2(
    const float* __restrict__ S3, const float* __restrict__ S2,
    const float* __restrict__ Wdfrac, const float* __restrict__ Wbsurv,
    const float* __restrict__ patp, const float* __restrict__ padp,
    const float* __restrict__ pamp,
    float* __restrict__ Wsg,
    float* __restrict__ WheirA, float* __restrict__ WheirD,
    float* __restrict__ WheirM, float* __restrict__ Wendow,
    float* __restrict__ O)
{
    int r = blockIdx.x * blockDim.x + threadIdx.x;
    if (r >= RR) return;

    float sa = 0.f, sd = 0.f, sm = 0.f, sg = 0.f, sc = 0.f;
    for (int b = 0; b < HB; b++) {
        sa += S3[(b * 3 + 0) * RR + r];
        sd += S3[(b * 3 + 1) * RR + r];
        sm += S3[(b * 3 + 2) * RR + r];
        sg += S2[(b * 2 + 0) * RR + r];
        sc += S2[(b * 2 + 1) * RR + r];
    }
    Wsg[r] = sg;

    float dfi = Wdfrac[r];
    float ra = sa * dfi;
    float rd = sd * dfi;
    float rm = sm * dfi;
    WheirA[r] = ra * 0.8f;                     // INHERIT_FRAC
    WheirD[r] = rd * 0.8f;
    WheirM[r] = rm * 0.8f;
    O[OUT_PATP + r] = patp[r] - ra * 0.2f;     // pool - (removed - heir)
    O[OUT_PADP + r] = padp[r] - rd * 0.2f;
    O[OUT_PAMP + r] = pamp[r] - rm * 0.2f;
    Wendow[r] = Wbsurv[r] / fmaxf(sc, 1.0f);   // BIRTH_ENDOW=1
}

// ---------------- kernel 5: agent apply ----------------
__global__ __launch_bounds__(256) void k_agent_apply(
    const int* __restrict__ reg, const float* __restrict__ greed,
    const float* __restrict__ atp, const float* __restrict__ adp,
    const float* __restrict__ amp,
    const float* __restrict__ Wsg, const float* __restrict__ Wdfrac,
    const float* __restrict__ WheirA, const float* __restrict__ WheirD,
    const float* __restrict__ WheirM, const float* __restrict__ Wendow,
    float* __restrict__ O)
{
    int i = blockIdx.x * blockDim.x + threadIdx.x;
    if (i >= NAG) return;
    int r = reg[i];
    float dfi = Wdfrac[r];
    float keep = 1.0f - dfi;
    float wn = (greed[i] + 1e-9f) / (Wsg[r] + EPS);
    O[OUT_ATP + i] = atp[i] * keep + wn * WheirA[r] + Wendow[r];
    O[OUT_ADP + i] = adp[i] * keep + wn * WheirD[r];
    O[OUT_AMP + i] = amp[i] * keep + wn * WheirM[r];
}

extern "C" void kernel_launch(void* const* d_in, const int* in_sizes, int n_in,
                              void* d_out, int out_size, void* d_ws, size_t ws_size,
                              hipStream_t stream) {
    const float* aec       = (const float*)d_in[0];
    const float* gdp_pc    = (const float*)d_in[1];
    const float* gdp_ema   = (const float*)d_in[2];
    const float* gdp_base  = (const float*)d_in[3];
    const float* dev_in    = (const float*)d_in[4];
    const float* sink_use  = (const float*)d_in[5];
    const float* sink_cap  = (const float*)d_in[6];
    const float* haz_base  = (const float*)d_in[7];
    const float* pop_age   = (const float*)d_in[8];
    const float* population= (const float*)d_in[9];
    const float* aging     = (const float*)d_in[10];
    const float* asfr      = (const float*)d_in[11];
    const float* distance  = (const float*)d_in[12];
    const float* cw        = (const float*)d_in[13];
    const float* pw        = (const float*)d_in[14];
    const float* cbase     = (const float*)d_in[15];
    const float* lbase     = (const float*)d_in[16];
    const float* greed     = (const float*)d_in[17];
    const float* eATP      = (const float*)d_in[18];
    const float* eADP      = (const float*)d_in[19];
    const float* eAMP      = (const float*)d_in[20];
    const float* patp      = (const float*)d_in[21];
    const float* padp      = (const float*)d_in[22];
    const float* pamp      = (const float*)d_in[23];
    const int*   nbr       = (const int*)d_in[24];
    const int*   reg       = (const int*)d_in[25];

    float* O = (float*)d_out;

    // -------- workspace layout (f32) --------
    float* W = (float*)d_ws;
    float* Wpa    = W;                    // R*A      = 413696
    float* Wdfrac = Wpa    + RR * AA;     // R
    float* Wbsurv = Wdfrac + RR;          // R
    float* Wattr  = Wbsurv + RR;          // R
    float* Wgdist = Wattr  + RR;          // R*K      = 131072
    float* Wash   = Wgdist + RR * KK;     // R*22
    float* Wmove  = Wash   + RR * 22;     // R*K
    float* Wscal  = Wmove  + RR * KK;     // 2 (zeroed)
    float* Wsg    = Wscal  + 2;           // R
    float* WheirA = Wsg    + RR;          // R
    float* WheirD = WheirA + RR;          // R
    float* WheirM = WheirD + RR;          // R
    float* Wendow = WheirM + RR;          // R
    float* S3     = Wendow + RR;          // HB*3*R = 1572864
    float* S2     = S3 + HB * 3 * RR;     // HB*2*R = 1048576
    float* Smig   = S2 + HB * 2 * RR;     // NCHUNK*22*R = 1441792
    // total ~= 4.86M floats ~= 18.6 MB

    k_zero<<<1, 64, 0, stream>>>(Wscal, 2);

    k_region1<<<RR / 256, 256, 0, stream>>>(
        aec, gdp_pc, gdp_ema, gdp_base, dev_in, sink_use, sink_cap, haz_base,
        pop_age, population, aging, asfr, distance, nbr,
        Wpa, Wdfrac, Wbsurv, Wattr, Wgdist, Wscal,
        O + OUT_GDP, O + OUT_DEV, O + OUT_H);

    k_migrate_a<<<RR / 256, 256, 0, stream>>>(nbr, Wattr, Wgdist, Wscal, Wpa, Wash, Wmove);

    k_migrate_b<<<NRANGE * NCHUNK, 256, 0, stream>>>(nbr, Wash, Wmove, Smig);

    k_finalize<<<RR / 256, 256, 0, stream>>>(Wpa, Smig, cw, pw, cbase, lbase, O);

    k_hist<<<2 * HB, 256, 0, stream>>>(reg, greed, eATP, eADP, eAMP, S3, S2);

    k_region2<<<RR / 256, 256, 0, stream>>>(S3, S2, Wdfrac, Wbsurv,
                                            patp, padp, pamp,
                                            Wsg, WheirA, WheirD, WheirM, Wendow, O);

    k_agent_apply<<<NAG / 256, 256, 0, stream>>>(reg, greed, eATP, eADP, eAMP,
                                                 Wsg, Wdfrac,
                                                 WheirA, WheirD, WheirM, Wendow, O);
}

// Round 4
// 307.558 us; speedup vs baseline: 4.4563x; 1.2329x over previous
//
#include <hip/hip_runtime.h>
#include <hip/hip_bf16.h>

#define RR 4096
#define AA 101
#define KK 32
#define NAG 4000000
#define NPAIR (NAG / 2)

#define DR 512          // dest regions per migrate range-block
#define NRANGE 8        // RR / DR
#define NCHUNK 16       // edge chunks
#define EPB (RR * KK / NCHUNK)   // 8192 edges per chunk
#define CH 8            // reduce chunks per sum

static constexpr float EPS  = 1e-9f;
static constexpr float DT   = 1.0f / 365.0f;
static constexpr float FRAC_MOVE = 0.02f / 365.0f;   // RATE_ANN*dt, within [0,0.25]

// ---------------- d_out offsets (f32 elements, return order) ----------------
#define OUT_POP   0
#define OUT_POPN  413696
#define OUT_GDP   417792
#define OUT_DEV   421888
#define OUT_H     425984
#define OUT_CONS  430080
#define OUT_LAB   434176
#define OUT_PSR   438272
#define OUT_DEP   442368
#define OUT_ATP   446464
#define OUT_ADP   4446464
#define OUT_AMP   8446464
#define OUT_PATP  12446464
#define OUT_PADP  12450560
#define OUT_PAMP  12454656

static __device__ __forceinline__ float clampf(float x, float lo, float hi) {
    return fminf(fmaxf(x, lo), hi);
}

// ---------------- kernel: zero tiny accumulators ----------------
__global__ void k_zero(float* __restrict__ p, int n) {
    int i = blockIdx.x * blockDim.x + threadIdx.x;
    if (i < n) p[i] = 0.0f;
}

// ---------------- kernel 1: per-region stage 1 ----------------
__global__ __launch_bounds__(64) void k_region1(
    const float* __restrict__ aec, const float* __restrict__ gdp_pc,
    const float* __restrict__ gdp_ema_in, const float* __restrict__ gdp_base,
    const float* __restrict__ dev_in, const float* __restrict__ sink_use,
    const float* __restrict__ sink_cap, const float* __restrict__ haz_base,
    const float* __restrict__ pop_age, const float* __restrict__ population,
    const float* __restrict__ aging, const float* __restrict__ asfr,
    const float* __restrict__ distance, const int* __restrict__ nbr,
    float* __restrict__ Wpa, float* __restrict__ Wdfrac, float* __restrict__ Wbsurv,
    float* __restrict__ Wattr, float* __restrict__ Wgdist, float* __restrict__ Wscal,
    float* __restrict__ out_gdp, float* __restrict__ out_dev,
    float* __restrict__ out_H)
{
    int r = blockIdx.x * 64 + threadIdx.x;
    if (r >= RR) return;

    float aec_norm = clampf(aec[r], 0.0f, 1.0f);
    float gprev = gdp_ema_in[r];
    float gema  = gprev * 0.9f + 0.1f * gdp_pc[r];
    float base  = gdp_base[r];
    float g_ratio = logf(fmaxf(gema / (base + EPS), 1e-6f));
    float g_term  = clampf(0.5f + 0.5f * tanhf(0.5f * g_ratio), 0.0f, 1.0f);
    float util = clampf(sink_use[r] / (sink_cap[r] + EPS), 0.0f, 1.0f);
    float H = clampf(0.5f * aec_norm + 0.4f * g_term + 0.1f * (1.0f - util), 0.0f, 1.0f);
    float dev_proxy = clampf(0.5f + 0.5f * tanhf(0.3f * g_ratio), 0.0f, 1.0f);
    float dev = dev_in[r] * 0.99f + 0.01f * dev_proxy;

    out_gdp[r] = gema;
    out_dev[r] = dev;
    out_H[r]   = H;

    float m_neon  = expf(-2.0f * H);
    float m_child = expf(-1.5f * H);
    float m_adult = expf(-1.0f * H);
    float hazmul = 1.0f + 0.5f * util;

    float pop_sum = 0.f, surv_sum = 0.f, haz05 = 0.f, haz0 = 0.f;
    float b_sum = 0.f, surv_prev = 0.f, pa0 = 0.f;

    for (int a = 0; a < AA; a++) {
        float mult = (a == 0) ? m_neon : ((a < 15) ? m_child : m_adult);
        float hz = clampf(haz_base[a] * mult * hazmul, 0.0f, 5.0f);
        float p = pop_age[r * AA + a];
        float s = p * expf(-hz * DT);
        pop_sum += p;
        surv_sum += s;
        if (a < 5) haz05 += hz;
        if (a == 0) haz0 = hz;
        float Md = aging[a * AA + a];
        float pa;
        if (a == 0) {
            pa = s * Md;
            pa0 = pa;
        } else {
            float Ms = aging[(a - 1) * AA + a];
            pa = s * Md + surv_prev * Ms;
            Wpa[r * AA + a] = pa;
        }
        surv_prev = s;
        if (a >= 15 && a < 50) b_sum += 0.5f * pa * asfr[a - 15];
    }

    float deaths = fmaxf(pop_sum - surv_sum, 0.0f);
    float dfrac = clampf(deaths / (population[r] + EPS), 0.0f, 0.99f);
    Wdfrac[r] = dfrac;

    float surv_u5 = expf(-haz05);
    float F_dev = clampf(expf(-dev), 0.5f, 1.5f);                      // THETA_DEV=1
    float F_rep = clampf(0.995f / fmaxf(surv_u5, 0.001f), 0.5f, 1.8f); // PHI_REP=1
    float g_growth = logf(fmaxf(gema + EPS, 1e-6f)) - logf(fmaxf(gprev + EPS, 1e-6f));
    float F_cyc = clampf(expf(-5.0f * fmaxf(-g_growth, 0.0f)), 0.6f, 1.2f);
    float F_total = clampf(F_dev * F_rep * F_cyc, 0.4f, 1.8f);
    float births = fmaxf(b_sum * F_total * DT, 0.0f);
    float bsurv = births * expf(-haz0 * DT);
    Wbsurv[r] = bsurv;
    Wpa[r * AA + 0] = pa0 + bsurv;

    float attr = 0.6f * (gdp_pc[r] / (base + EPS)) + 0.4f * (0.5f + 0.5f * aec_norm);
    Wattr[r] = attr;
    atomicAdd(&Wscal[0], attr);

    float dsum = 0.f;
    for (int k = 0; k < KK; k++) {
        int idx = nbr[r * KK + k];
        float d = distance[(size_t)r * RR + idx];
        Wgdist[r * KK + k] = d;
        dsum += d;
    }
    atomicAdd(&Wscal[1], dsum);
}

// ---------------- kernel 2a: migration weights + outflow ----------------
__global__ __launch_bounds__(64) void k_migrate_a(
    const int* __restrict__ nbr, const float* __restrict__ Wattr,
    const float* __restrict__ Wgdist, const float* __restrict__ Wscal,
    float* __restrict__ Wpa, float* __restrict__ Wash, float* __restrict__ Wmove)
{
    int r = blockIdx.x * 64 + threadIdx.x;
    if (r >= RR) return;

    float amean = Wscal[0] / (float)RR;
    float dmean = Wscal[1] / (float)(RR * KK);
    float inv_am = 1.0f / (amean + EPS);
    float inv_dm = 1.0f / (dmean + EPS);

    float mobile[22];
    float msum = 0.f;
#pragma unroll
    for (int f = 0; f < 22; f++) {
        mobile[f] = Wpa[r * AA + 18 + f];
        msum += mobile[f];
    }

    float wv[KK];
    float wsum = 0.f;
#pragma unroll
    for (int k = 0; k < KK; k++) {
        int idx = nbr[r * KK + k];
        float an = Wattr[idx] * inv_am;
        float cost = 1.0f + Wgdist[r * KK + k] * inv_dm;
        float w = fmaxf(an / cost, 0.0f);
        wv[k] = w;
        wsum += w;
    }

    float out_R = msum * FRAC_MOVE;
    float invw = 1.0f / (wsum + EPS);
    float move_sum = out_R * wsum * invw;   // out_R * sum(w_norm)
    float inv_ms = 1.0f / (msum + EPS);

#pragma unroll
    for (int f = 0; f < 22; f++) {
        float ash = mobile[f] * inv_ms;
        Wash[r * 22 + f] = ash;
        Wpa[r * AA + 18 + f] = mobile[f] - ash * move_sum;
    }
#pragma unroll
    for (int k = 0; k < KK; k++) {
        Wmove[r * KK + k] = out_R * wv[k] * invw;
    }
}

// ---------------- kernel 2b: inflow scatter, LDS range-split, atomic-free ----------------
__global__ __launch_bounds__(256) void k_migrate_b(
    const int* __restrict__ nbr, const float* __restrict__ Wash,
    const float* __restrict__ Wmove, float* __restrict__ Smig)
{
    __shared__ float h[22 * DR];   // 45056 B
    int range = blockIdx.x & (NRANGE - 1);
    int chunk = blockIdx.x >> 3;
    int d0 = range * DR;

    for (int i = threadIdx.x; i < 22 * DR; i += 256) h[i] = 0.0f;
    __syncthreads();

    int tend = (chunk + 1) * EPB;
    for (int t = chunk * EPB + threadIdx.x; t < tend; t += 256) {
        int idx = nbr[t];
        if (idx >= d0 && idx < d0 + DR) {
            int r = t >> 5;                 // K=32
            float mv = Wmove[t];
            const float* ash = &Wash[r * 22];
            int dl = idx - d0;
#pragma unroll
            for (int f = 0; f < 22; f++) {
                atomicAdd(&h[f * DR + dl], ash[f] * mv);
            }
        }
    }
    __syncthreads();

    for (int i = threadIdx.x; i < 22 * DR; i += 256) {
        int f = i / DR;
        int d = i - f * DR;
        Smig[(chunk * 22 + f) * RR + d0 + d] = h[i];
    }
}

// ---------------- kernel 3: finalize population + region stats ----------------
__global__ __launch_bounds__(64) void k_finalize(
    const float* __restrict__ Wpa, const float* __restrict__ Smig,
    const float* __restrict__ cw, const float* __restrict__ pw,
    const float* __restrict__ cbase, const float* __restrict__ lbase,
    float* __restrict__ O)
{
    int r = blockIdx.x * 64 + threadIdx.x;
    if (r >= RR) return;

    float psum = 0.f, cdot = 0.f, ldot = 0.f, work = 0.f, young = 0.f, old = 0.f;
    for (int a = 0; a < AA; a++) {
        float v = Wpa[r * AA + a];
        if (a >= 18 && a < 40) {
            int f = a - 18;
            float add = 0.f;
#pragma unroll
            for (int c = 0; c < NCHUNK; c++)
                add += Smig[(c * 22 + f) * RR + r];
            v += add;
        }
        v = fmaxf(v, 0.0f);
        O[OUT_POP + r * AA + a] = v;
        psum += v;
        cdot += v * cw[a];
        ldot += v * pw[a];
        if (a < 15) young += v;
        else if (a < 65) work += v;
        else old += v;
    }
    O[OUT_POPN + r] = fmaxf(psum, 0.0f);
    O[OUT_CONS + r] = clampf(cdot / (cbase[r] + EPS), 0.25f, 4.0f);
    O[OUT_LAB + r]  = clampf(ldot / (lbase[r] + EPS), 0.2f, 1.2f);
    O[OUT_PSR + r]  = work / (old + EPS);
    O[OUT_DEP + r]  = (young + old) / (work + EPS);
}

// ---------------- kernel 4: agent segment sums via LDS histograms ----------------
// blocks [0,HB): {atp,adp,amp} -> S3[b*3*RR + s*RR + r]
// blocks [HB,2*HB): {greed,count} -> S2[b*2*RR + s*RR + r]
// 512 threads (8 waves), x2-vectorized agent loads.
__global__ __launch_bounds__(512) void k_hist(
    const int* __restrict__ reg, const float* __restrict__ greed,
    const float* __restrict__ atp, const float* __restrict__ adp,
    const float* __restrict__ amp,
    float* __restrict__ S3, float* __restrict__ S2, int HB)
{
    __shared__ float h[3 * RR];   // 48 KiB
    const int2*   reg2 = (const int2*)reg;
    int bid = blockIdx.x;
    if (bid < HB) {
        const float2* a2 = (const float2*)atp;
        const float2* d2 = (const float2*)adp;
        const float2* m2 = (const float2*)amp;
        for (int i = threadIdx.x; i < 3 * RR; i += 512) h[i] = 0.0f;
        __syncthreads();
        for (int p = bid * 512 + threadIdx.x; p < NPAIR; p += HB * 512) {
            int2 rp = reg2[p];
            float2 av = a2[p];
            float2 dv = d2[p];
            float2 mv = m2[p];
            atomicAdd(&h[rp.x],          av.x);
            atomicAdd(&h[RR + rp.x],     dv.x);
            atomicAdd(&h[2 * RR + rp.x], mv.x);
            atomicAdd(&h[rp.y],          av.y);
            atomicAdd(&h[RR + rp.y],     dv.y);
            atomicAdd(&h[2 * RR + rp.y], mv.y);
        }
        __syncthreads();
        for (int i = threadIdx.x; i < 3 * RR; i += 512)
            S3[bid * 3 * RR + i] = h[i];
    } else {
        int b = bid - HB;
        const float2* g2 = (const float2*)greed;
        for (int i = threadIdx.x; i < 2 * RR; i += 512) h[i] = 0.0f;
        __syncthreads();
        for (int p = b * 512 + threadIdx.x; p < NPAIR; p += HB * 512) {
            int2 rp = reg2[p];
            float2 gv = g2[p];
            atomicAdd(&h[rp.x],      gv.x + 1e-9f);
            atomicAdd(&h[RR + rp.x], 1.0f);
            atomicAdd(&h[rp.y],      gv.y + 1e-9f);
            atomicAdd(&h[RR + rp.y], 1.0f);
        }
        __syncthreads();
        for (int i = threadIdx.x; i < 2 * RR; i += 512)
            S2[b * 2 * RR + i] = h[i];
    }
}

// ---------------- kernel 4a: two-level partial reduction ----------------
// 5 logical sums: s=0 atp, 1 adp, 2 amp, 3 greed, 4 count.
// T[(s*CH + c)*RR + r] = sum over b in chunk c.
__global__ __launch_bounds__(256) void k_reduce(
    const float* __restrict__ S3, const float* __restrict__ S2,
    float* __restrict__ T, int HB)
{
    int tid = blockIdx.x * 256 + threadIdx.x;
    if (tid >= 5 * CH * RR) return;
    int r = tid & (RR - 1);
    int rest = tid >> 12;
    int c = rest & (CH - 1);
    int s = rest >> 3;
    int bpc = HB / CH;
    int b0 = c * bpc;
    float acc = 0.f;
    if (s < 3) {
        for (int b = b0; b < b0 + bpc; b++)
            acc += S3[(b * 3 + s) * RR + r];
    } else {
        int ss = s - 3;
        for (int b = b0; b < b0 + bpc; b++)
            acc += S2[(b * 2 + ss) * RR + r];
    }
    T[(s * CH + c) * RR + r] = acc;
}

// ---------------- kernel 4b: final partials + heir pools / pool outputs ----------------
__global__ __launch_bounds__(64) void k_region2(
    const float* __restrict__ T,
    const float* __restrict__ Wdfrac, const float* __restrict__ Wbsurv,
    const float* __restrict__ patp, const float* __restrict__ padp,
    const float* __restrict__ pamp,
    float* __restrict__ Wsg,
    float* __restrict__ WheirA, float* __restrict__ WheirD,
    float* __restrict__ WheirM, float* __restrict__ Wendow,
    float* __restrict__ O)
{
    int r = blockIdx.x * 64 + threadIdx.x;
    if (r >= RR) return;

    float sums[5];
#pragma unroll
    for (int s = 0; s < 5; s++) {
        float acc = 0.f;
#pragma unroll
        for (int c = 0; c < CH; c++)
            acc += T[(s * CH + c) * RR + r];
        sums[s] = acc;
    }
    float sa = sums[0], sd = sums[1], sm = sums[2], sg = sums[3], sc = sums[4];
    Wsg[r] = sg;

    float dfi = Wdfrac[r];
    float ra = sa * dfi;
    float rd = sd * dfi;
    float rm = sm * dfi;
    WheirA[r] = ra * 0.8f;                     // INHERIT_FRAC
    WheirD[r] = rd * 0.8f;
    WheirM[r] = rm * 0.8f;
    O[OUT_PATP + r] = patp[r] - ra * 0.2f;     // pool - (removed - heir)
    O[OUT_PADP + r] = padp[r] - rd * 0.2f;
    O[OUT_PAMP + r] = pamp[r] - rm * 0.2f;
    Wendow[r] = Wbsurv[r] / fmaxf(sc, 1.0f);   // BIRTH_ENDOW=1
}

// ---------------- kernel 5: agent apply, x2 vectorized ----------------
__global__ __launch_bounds__(256) void k_agent_apply(
    const int* __restrict__ reg, const float* __restrict__ greed,
    const float* __restrict__ atp, const float* __restrict__ adp,
    const float* __restrict__ amp,
    const float* __restrict__ Wsg, const float* __restrict__ Wdfrac,
    const float* __restrict__ WheirA, const float* __restrict__ WheirD,
    const float* __restrict__ WheirM, const float* __restrict__ Wendow,
    float* __restrict__ O)
{
    int p = blockIdx.x * 256 + threadIdx.x;
    if (p >= NPAIR) return;
    const int2*   reg2 = (const int2*)reg;
    const float2* g2 = (const float2*)greed;
    const float2* a2 = (const float2*)atp;
    const float2* d2 = (const float2*)adp;
    const float2* m2 = (const float2*)amp;

    int2 rp = reg2[p];
    float2 gv = g2[p];
    float2 av = a2[p];
    float2 dv = d2[p];
    float2 mv = m2[p];

    float dfx = Wdfrac[rp.x], dfy = Wdfrac[rp.y];
    float wnx = (gv.x + 1e-9f) / (Wsg[rp.x] + EPS);
    float wny = (gv.y + 1e-9f) / (Wsg[rp.y] + EPS);

    float2 oa, od, om;
    oa.x = av.x * (1.0f - dfx) + wnx * WheirA[rp.x] + Wendow[rp.x];
    oa.y = av.y * (1.0f - dfy) + wny * WheirA[rp.y] + Wendow[rp.y];
    od.x = dv.x * (1.0f - dfx) + wnx * WheirD[rp.x];
    od.y = dv.y * (1.0f - dfy) + wny * WheirD[rp.y];
    om.x = mv.x * (1.0f - dfx) + wnx * WheirM[rp.x];
    om.y = mv.y * (1.0f - dfy) + wny * WheirM[rp.y];

    ((float2*)(O + OUT_ATP))[p] = oa;
    ((float2*)(O + OUT_ADP))[p] = od;
    ((float2*)(O + OUT_AMP))[p] = om;
}

extern "C" void kernel_launch(void* const* d_in, const int* in_sizes, int n_in,
                              void* d_out, int out_size, void* d_ws, size_t ws_size,
                              hipStream_t stream) {
    const float* aec       = (const float*)d_in[0];
    const float* gdp_pc    = (const float*)d_in[1];
    const float* gdp_ema   = (const float*)d_in[2];
    const float* gdp_base  = (const float*)d_in[3];
    const float* dev_in    = (const float*)d_in[4];
    const float* sink_use  = (const float*)d_in[5];
    const float* sink_cap  = (const float*)d_in[6];
    const float* haz_base  = (const float*)d_in[7];
    const float* pop_age   = (const float*)d_in[8];
    const float* population= (const float*)d_in[9];
    const float* aging     = (const float*)d_in[10];
    const float* asfr      = (const float*)d_in[11];
    const float* distance  = (const float*)d_in[12];
    const float* cw        = (const float*)d_in[13];
    const float* pw        = (const float*)d_in[14];
    const float* cbase     = (const float*)d_in[15];
    const float* lbase     = (const float*)d_in[16];
    const float* greed     = (const float*)d_in[17];
    const float* eATP      = (const float*)d_in[18];
    const float* eADP      = (const float*)d_in[19];
    const float* eAMP      = (const float*)d_in[20];
    const float* patp      = (const float*)d_in[21];
    const float* padp      = (const float*)d_in[22];
    const float* pamp      = (const float*)d_in[23];
    const int*   nbr       = (const int*)d_in[24];
    const int*   reg       = (const int*)d_in[25];

    float* O = (float*)d_out;

    // -------- workspace layout (f32) --------
    float* W = (float*)d_ws;
    float* Wpa    = W;                    // R*A      = 413696
    float* Wdfrac = Wpa    + RR * AA;     // R
    float* Wbsurv = Wdfrac + RR;          // R
    float* Wattr  = Wbsurv + RR;          // R
    float* Wgdist = Wattr  + RR;          // R*K
    float* Wash   = Wgdist + RR * KK;     // R*22
    float* Wmove  = Wash   + RR * 22;     // R*K
    float* Wscal  = Wmove  + RR * KK;     // 2 (zeroed)
    float* Wsg    = Wscal  + 2;           // R
    float* WheirA = Wsg    + RR;          // R
    float* WheirD = WheirA + RR;          // R
    float* WheirM = WheirD + RR;          // R
    float* Wendow = WheirM + RR;          // R
    float* Smig   = Wendow + RR;          // NCHUNK*22*R
    float* T      = Smig + NCHUNK * 22 * RR;  // 5*CH*R
    float* S3     = T + 5 * CH * RR;      // HB*3*R
    // S2 follows S3 (size depends on HB)

    size_t fixed = (size_t)(S3 - W);      // floats before S3
    // pick largest HB in {256,192,128} that fits: S3+S2 = HB*5*RR floats
    int HB = 128;
    if ((fixed + (size_t)256 * 5 * RR) * 4 <= ws_size) HB = 256;
    else if ((fixed + (size_t)192 * 5 * RR) * 4 <= ws_size) HB = 192;
    float* S2 = S3 + (size_t)HB * 3 * RR;

    k_zero<<<1, 64, 0, stream>>>(Wscal, 2);

    k_region1<<<RR / 64, 64, 0, stream>>>(
        aec, gdp_pc, gdp_ema, gdp_base, dev_in, sink_use, sink_cap, haz_base,
        pop_age, population, aging, asfr, distance, nbr,
        Wpa, Wdfrac, Wbsurv, Wattr, Wgdist, Wscal,
        O + OUT_GDP, O + OUT_DEV, O + OUT_H);

    k_migrate_a<<<RR / 64, 64, 0, stream>>>(nbr, Wattr, Wgdist, Wscal, Wpa, Wash, Wmove);

    k_migrate_b<<<NRANGE * NCHUNK, 256, 0, stream>>>(nbr, Wash, Wmove, Smig);

    k_finalize<<<RR / 64, 64, 0, stream>>>(Wpa, Smig, cw, pw, cbase, lbase, O);

    k_hist<<<2 * HB, 512, 0, stream>>>(reg, greed, eATP, eADP, eAMP, S3, S2, HB);

    k_reduce<<<(5 * CH * RR) / 256, 256, 0, stream>>>(S3, S2, T, HB);

    k_region2<<<RR / 64, 64, 0, stream>>>(T, Wdfrac, Wbsurv,
                                          patp, padp, pamp,
                                          Wsg, WheirA, WheirD, WheirM, Wendow, O);

    k_agent_apply<<<(NPAIR + 255) / 256, 256, 0, stream>>>(
        reg, greed, eATP, eADP, eAMP,
        Wsg, Wdfrac, WheirA, WheirD, WheirM, Wendow, O);
}

// Round 5
// 222.580 us; speedup vs baseline: 6.1577x; 1.3818x over previous
//
#include <hip/hip_runtime.h>

#define RR 4096
#define AA 101
#define PAD_W 104
#define KK 32
#define NAG 4000000

#define NCHUNK 32
#define DR 512
#define NRANGE 8
#define EPB (RR * KK / NCHUNK)   // 4096 edges per chunk
#define CH 8

static constexpr float EPS  = 1e-9f;
static constexpr float DT   = 1.0f / 365.0f;
static constexpr float FRAC_MOVE = 0.02f / 365.0f;

static constexpr float SC13  = 8192.0f;          // 2^13
static constexpr float INV13 = 1.0f / 8192.0f;
static constexpr float SC20  = 1048576.0f;       // 2^20
static constexpr float INV20 = 1.0f / 1048576.0f;
static constexpr float SC18  = 262144.0f;        // 2^18
static constexpr float INV18 = 1.0f / 262144.0f;

// ---------------- d_out offsets (f32 elements, return order) ----------------
#define OUT_POP   0
#define OUT_POPN  413696
#define OUT_GDP   417792
#define OUT_DEV   421888
#define OUT_H     425984
#define OUT_CONS  430080
#define OUT_LAB   434176
#define OUT_PSR   438272
#define OUT_DEP   442368
#define OUT_ATP   446464
#define OUT_ADP   4446464
#define OUT_AMP   8446464
#define OUT_PATP  12446464
#define OUT_PADP  12450560
#define OUT_PAMP  12454656

static __device__ __forceinline__ float clampf(float x, float lo, float hi) {
    return fminf(fmaxf(x, lo), hi);
}
static __device__ __forceinline__ float wred(float x) {
#pragma unroll
    for (int m = 32; m; m >>= 1) x += __shfl_xor(x, m);
    return x;
}

__global__ void k_zero(float* __restrict__ p, int n) {
    int i = blockIdx.x * blockDim.x + threadIdx.x;
    if (i < n) p[i] = 0.0f;
}

// ---------------- kernel 1: per-region stage 1, wave-per-region ----------------
__global__ __launch_bounds__(256) void k_region1(
    const float* __restrict__ aec, const float* __restrict__ gdp_pc,
    const float* __restrict__ gdp_ema_in, const float* __restrict__ gdp_base,
    const float* __restrict__ dev_in, const float* __restrict__ sink_use,
    const float* __restrict__ sink_cap, const float* __restrict__ haz_base,
    const float* __restrict__ pop_age, const float* __restrict__ population,
    const float* __restrict__ aging, const float* __restrict__ asfr,
    const float* __restrict__ distance, const int* __restrict__ nbr,
    float* __restrict__ Wpa, float* __restrict__ Wdfrac, float* __restrict__ Wbsurv,
    float* __restrict__ Wattr, float* __restrict__ Wgdist, float* __restrict__ Wscal,
    float* __restrict__ O)
{
    int wid = threadIdx.x >> 6, lane = threadIdx.x & 63;
    int r = blockIdx.x * 4 + wid;

    float aec_norm = clampf(aec[r], 0.0f, 1.0f);
    float gprev = gdp_ema_in[r];
    float gema  = gprev * 0.9f + 0.1f * gdp_pc[r];
    float base  = gdp_base[r];
    float g_ratio = logf(fmaxf(gema / (base + EPS), 1e-6f));
    float g_term  = clampf(0.5f + 0.5f * tanhf(0.5f * g_ratio), 0.0f, 1.0f);
    float util = clampf(sink_use[r] / (sink_cap[r] + EPS), 0.0f, 1.0f);
    float H = clampf(0.5f * aec_norm + 0.4f * g_term + 0.1f * (1.0f - util), 0.0f, 1.0f);
    float dev_proxy = clampf(0.5f + 0.5f * tanhf(0.3f * g_ratio), 0.0f, 1.0f);
    float dev = dev_in[r] * 0.99f + 0.01f * dev_proxy;

    float m_neon  = expf(-2.0f * H);
    float m_child = expf(-1.5f * H);
    float m_adult = expf(-1.0f * H);
    float hazmul = 1.0f + 0.5f * util;

    int a0 = lane * 2, a1 = a0 + 1;
    bool v0 = (a0 < AA), v1 = (a1 < AA);

    float p0 = 0.f, p1 = 0.f, hz0 = 0.f, hz1 = 0.f;
    if (v0) {
        p0 = pop_age[r * AA + a0];
        float mult = (a0 == 0) ? m_neon : ((a0 < 15) ? m_child : m_adult);
        hz0 = clampf(haz_base[a0] * mult * hazmul, 0.0f, 5.0f);
    }
    if (v1) {
        p1 = pop_age[r * AA + a1];
        float mult = (a1 < 15) ? m_child : m_adult;
        hz1 = clampf(haz_base[a1] * mult * hazmul, 0.0f, 5.0f);
    }
    float s0 = v0 ? p0 * expf(-hz0 * DT) : 0.f;
    float s1 = v1 ? p1 * expf(-hz1 * DT) : 0.f;
    float sp = __shfl_up(s1, 1);   // s[a0-1]

    float Md0 = 0.f, Md1 = 0.f, Ms0 = 0.f, Ms1 = 0.f;
    if (v0) { Md0 = aging[a0 * AA + a0]; if (a0 > 0) Ms0 = aging[(a0 - 1) * AA + a0]; }
    if (v1) { Md1 = aging[a1 * AA + a1]; Ms1 = aging[(a1 - 1) * AA + a1]; }

    float pa0 = v0 ? ((a0 == 0) ? s0 * Md0 : s0 * Md0 + sp * Ms0) : 0.f;
    float pa1 = v1 ? (s1 * Md1 + s0 * Ms1) : 0.f;

    if (v0 && a0 > 0) Wpa[r * PAD_W + a0] = pa0;
    if (v1)           Wpa[r * PAD_W + a1] = pa1;

    float pop_sum  = wred(p0 + p1);
    float surv_sum = wred(s0 + s1);
    float haz05 = wred(((v0 && a0 < 5) ? hz0 : 0.f) + ((v1 && a1 < 5) ? hz1 : 0.f));
    float bs0 = (a0 >= 15 && a0 < 50) ? 0.5f * pa0 * asfr[a0 - 15] : 0.f;
    float bs1 = (a1 >= 15 && a1 < 50) ? 0.5f * pa1 * asfr[a1 - 15] : 0.f;
    float b_sum = wred(bs0 + bs1);

    float dc = 0.f;
    if (lane < KK) {
        int idx = nbr[r * KK + lane];
        float d = distance[(size_t)r * RR + idx];
        Wgdist[r * KK + lane] = d;
        dc = d;
    }
    float dsum = wred(dc);

    if (lane == 0) {
        O[OUT_GDP + r] = gema;
        O[OUT_DEV + r] = dev;
        O[OUT_H + r]   = H;

        float deaths = fmaxf(pop_sum - surv_sum, 0.0f);
        Wdfrac[r] = clampf(deaths / (population[r] + EPS), 0.0f, 0.99f);

        float surv_u5 = expf(-haz05);
        float F_dev = clampf(expf(-dev), 0.5f, 1.5f);
        float F_rep = clampf(0.995f / fmaxf(surv_u5, 0.001f), 0.5f, 1.8f);
        float g_growth = logf(fmaxf(gema + EPS, 1e-6f)) - logf(fmaxf(gprev + EPS, 1e-6f));
        float F_cyc = clampf(expf(-5.0f * fmaxf(-g_growth, 0.0f)), 0.6f, 1.2f);
        float F_total = clampf(F_dev * F_rep * F_cyc, 0.4f, 1.8f);
        float births = fmaxf(b_sum * F_total * DT, 0.0f);
        float bsurv = births * expf(-hz0 * DT);       // hz0 on lane0 = haz[0]
        Wbsurv[r] = bsurv;
        Wpa[r * PAD_W + 0] = pa0 + bsurv;             // lane0 pa0 = pa(age 0)

        float attr = 0.6f * (gdp_pc[r] / (base + EPS)) + 0.4f * (0.5f + 0.5f * aec_norm);
        Wattr[r] = attr;
        atomicAdd(&Wscal[0], attr);
        atomicAdd(&Wscal[1], dsum);
    }
}

// ---------------- kernel 2a: migration weights + outflow, wave-per-region ----------------
__global__ __launch_bounds__(256) void k_migrate_a(
    const int* __restrict__ nbr, const float* __restrict__ Wattr,
    const float* __restrict__ Wgdist, const float* __restrict__ Wscal,
    float* __restrict__ Wpa, float* __restrict__ Wash, float* __restrict__ Wmove)
{
    int wid = threadIdx.x >> 6, lane = threadIdx.x & 63;
    int r = blockIdx.x * 4 + wid;

    float inv_am = 1.0f / (Wscal[0] / (float)RR + EPS);
    float inv_dm = 1.0f / (Wscal[1] / (float)(RR * KK) + EPS);

    float mob = 0.f;
    if (lane < 22) mob = Wpa[r * PAD_W + 18 + lane];
    float msum = wred(lane < 22 ? mob : 0.f);

    float w = 0.f;
    if (lane < KK) {
        int idx = nbr[r * KK + lane];
        float an = Wattr[idx] * inv_am;
        float cost = 1.0f + Wgdist[r * KK + lane] * inv_dm;
        w = fmaxf(an / cost, 0.0f);
    }
    float wsum = wred(lane < KK ? w : 0.f);

    float out_R = msum * FRAC_MOVE;
    float invw = 1.0f / (wsum + EPS);
    float move_sum = out_R * wsum * invw;
    float inv_ms = 1.0f / (msum + EPS);

    if (lane < 22) {
        float ash = mob * inv_ms;
        Wash[r * 22 + lane] = ash;
        Wpa[r * PAD_W + 18 + lane] = mob - ash * move_sum;
    }
    if (lane < KK) Wmove[r * KK + lane] = out_R * w * invw;
}

// ---------------- kernel 2b: inflow scatter, u64-packed LDS histograms ----------------
__global__ __launch_bounds__(256) void k_migrate_b(
    const int* __restrict__ nbr, const float* __restrict__ Wash,
    const float* __restrict__ Wmove, float* __restrict__ Smig)
{
    __shared__ unsigned long long h[11 * DR];   // 45056 B
    int range = blockIdx.x & (NRANGE - 1);
    int chunk = blockIdx.x >> 3;
    int d0 = range * DR;

    for (int i = threadIdx.x; i < 11 * DR; i += 256) h[i] = 0ull;
    __syncthreads();

    int tend = (chunk + 1) * EPB;
    for (int t = chunk * EPB + threadIdx.x; t < tend; t += 256) {
        int idx = nbr[t];
        if (idx >= d0 && idx < d0 + DR) {
            int rsrc = t >> 5;
            float mv = Wmove[t];
            const float* ash = &Wash[rsrc * 22];
            int dl = idx - d0;
#pragma unroll
            for (int f = 0; f < 11; f++) {
                unsigned long long lo = __float2uint_rn(ash[2 * f] * mv * SC18);
                unsigned long long hi = __float2uint_rn(ash[2 * f + 1] * mv * SC18);
                atomicAdd(&h[f * DR + dl], lo | (hi << 32));
            }
        }
    }
    __syncthreads();

    for (int i = threadIdx.x; i < 11 * DR; i += 256) {
        int f = i / DR, d = i - f * DR;
        unsigned long long v = h[i];
        Smig[(chunk * 22 + 2 * f) * RR + d0 + d]     = (float)(unsigned int)v * INV18;
        Smig[(chunk * 22 + 2 * f + 1) * RR + d0 + d] = (float)(v >> 32) * INV18;
    }
}

// ---------------- kernel 4: agent segment sums, 2 packed u64 atomics/agent ----------------
template<int NB>
__global__ __launch_bounds__(512) void k_hist(
    const int* __restrict__ reg, const float* __restrict__ greed,
    const float* __restrict__ atp, const float* __restrict__ adp,
    const float* __restrict__ amp, float* __restrict__ S)
{
    __shared__ unsigned long long hAB[RR];    // atp | adp<<32   (x2^13)
    __shared__ unsigned long long hMGC[RR];   // amp | greed<<28 | count<<56
    for (int i = threadIdx.x; i < RR; i += 512) { hAB[i] = 0ull; hMGC[i] = 0ull; }
    __syncthreads();

    const int4*   reg4 = (const int4*)reg;
    const float4* g4 = (const float4*)greed;
    const float4* a4 = (const float4*)atp;
    const float4* d4 = (const float4*)adp;
    const float4* m4 = (const float4*)amp;
    const int NQ = NAG / 4;

    for (int q = blockIdx.x * 512 + threadIdx.x; q < NQ; q += NB * 512) {
        int4 rr = reg4[q];
        float4 gv = g4[q], av = a4[q], dv = d4[q], mv = m4[q];
#define DO1(RX, GX, AX, DX, MX) { \
        unsigned long long ai = __float2uint_rn((AX) * SC13); \
        unsigned long long di = __float2uint_rn((DX) * SC13); \
        unsigned long long mi = __float2uint_rn((MX) * SC13); \
        unsigned long long gi = __float2uint_rn(((GX) + 1e-9f) * SC20); \
        atomicAdd(&hAB[RX],  ai | (di << 32)); \
        atomicAdd(&hMGC[RX], mi | (gi << 28) | (1ull << 56)); }
        DO1(rr.x, gv.x, av.x, dv.x, mv.x)
        DO1(rr.y, gv.y, av.y, dv.y, mv.y)
        DO1(rr.z, gv.z, av.z, dv.z, mv.z)
        DO1(rr.w, gv.w, av.w, dv.w, mv.w)
#undef DO1
    }
    __syncthreads();

    int b = blockIdx.x;
    for (int i = threadIdx.x; i < RR; i += 512) {
        unsigned long long ab = hAB[i], mgc = hMGC[i];
        S[((size_t)0 * NB + b) * RR + i] = (float)(unsigned int)ab * INV13;
        S[((size_t)1 * NB + b) * RR + i] = (float)(ab >> 32) * INV13;
        S[((size_t)2 * NB + b) * RR + i] = (float)(mgc & 0xFFFFFFFull) * INV13;
        S[((size_t)3 * NB + b) * RR + i] = (float)((mgc >> 28) & 0xFFFFFFFull) * INV20;
        S[((size_t)4 * NB + b) * RR + i] = (float)(mgc >> 56);
    }
}

// ---------------- kernel: reduce hist partials + fold Smig -> Wadd ----------------
__global__ __launch_bounds__(256) void k_reduce(
    const float* __restrict__ S, const float* __restrict__ Smig,
    float* __restrict__ T, float* __restrict__ Wadd, int NB)
{
    int blk = blockIdx.x;
    if (blk < 640) {
        int tid = blk * 256 + threadIdx.x;      // < 5*8*4096
        int r = tid & (RR - 1);
        int c = (tid >> 12) & (CH - 1);
        int s = tid >> 15;
        int bpc = NB >> 3;
        float acc = 0.f;
        for (int b = c * bpc; b < (c + 1) * bpc; b++)
            acc += S[((size_t)s * NB + b) * RR + r];
        T[(s * CH + c) * RR + r] = acc;
    } else {
        int t2 = (blk - 640) * 256 + threadIdx.x;   // < 22*4096
        int f = t2 >> 12, rr = t2 & (RR - 1);
        float acc = 0.f;
#pragma unroll
        for (int c = 0; c < NCHUNK; c++)
            acc += Smig[(c * 22 + f) * RR + rr];
        Wadd[rr * 24 + f] = acc;
    }
}

// ---------------- kernel: finalize population (wave/region) + region2 ----------------
__global__ __launch_bounds__(256) void k_fin(
    const float* __restrict__ Wpa, const float* __restrict__ Wadd,
    const float* __restrict__ cw, const float* __restrict__ pw,
    const float* __restrict__ cbase, const float* __restrict__ lbase,
    const float* __restrict__ T,
    const float* __restrict__ Wdfrac, const float* __restrict__ Wbsurv,
    const float* __restrict__ patp, const float* __restrict__ padp,
    const float* __restrict__ pamp,
    float4* __restrict__ P4, float2* __restrict__ P2,
    float* __restrict__ O)
{
    int blk = blockIdx.x;
    if (blk < 1024) {
        int wid = threadIdx.x >> 6, lane = threadIdx.x & 63;
        int r = blk * 4 + wid;
        int a0 = lane * 2, a1 = a0 + 1;
        bool v0 = (a0 < AA), v1 = (a1 < AA);

        float va = 0.f, vb = 0.f;
        if (lane < 51) {
            float2 pp = *(const float2*)&Wpa[r * PAD_W + a0];
            va = pp.x; vb = pp.y;
        }
        if (a0 >= 18 && a0 < 40) {
            float2 ad = *(const float2*)&Wadd[r * 24 + (a0 - 18)];
            va += ad.x; vb += ad.y;
        }
        va = v0 ? fmaxf(va, 0.0f) : 0.f;
        vb = v1 ? fmaxf(vb, 0.0f) : 0.f;
        if (v0) O[OUT_POP + r * AA + a0] = va;
        if (v1) O[OUT_POP + r * AA + a1] = vb;

        float cw0 = v0 ? cw[a0] : 0.f, cw1 = v1 ? cw[a1] : 0.f;
        float pw0 = v0 ? pw[a0] : 0.f, pw1 = v1 ? pw[a1] : 0.f;

        float psum  = wred(va + vb);
        float cdot  = wred(va * cw0 + vb * cw1);
        float ldot  = wred(va * pw0 + vb * pw1);
        float young = wred(((a0 < 15) ? va : 0.f) + ((a1 < 15) ? vb : 0.f));
        float work  = wred(((a0 >= 15 && a0 < 65) ? va : 0.f) + ((a1 >= 15 && a1 < 65) ? vb : 0.f));
        float old   = wred(((a0 >= 65) ? va : 0.f) + ((a1 >= 65) ? vb : 0.f));

        if (lane == 0) {
            O[OUT_POPN + r] = fmaxf(psum, 0.0f);
            O[OUT_CONS + r] = clampf(cdot / (cbase[r] + EPS), 0.25f, 4.0f);
            O[OUT_LAB + r]  = clampf(ldot / (lbase[r] + EPS), 0.2f, 1.2f);
            O[OUT_PSR + r]  = work / (old + EPS);
            O[OUT_DEP + r]  = (young + old) / (work + EPS);
        }
    } else {
        int r = (blk - 1024) * 256 + threadIdx.x;
        if (r >= RR) return;
        float sums[5];
#pragma unroll
        for (int s = 0; s < 5; s++) {
            float acc = 0.f;
#pragma unroll
            for (int c = 0; c < CH; c++)
                acc += T[(s * CH + c) * RR + r];
            sums[s] = acc;
        }
        float dfi = Wdfrac[r];
        float ra = sums[0] * dfi;
        float rd = sums[1] * dfi;
        float rm = sums[2] * dfi;
        O[OUT_PATP + r] = patp[r] - ra * 0.2f;
        O[OUT_PADP + r] = padp[r] - rd * 0.2f;
        O[OUT_PAMP + r] = pamp[r] - rm * 0.2f;
        P4[r] = make_float4(1.0f - dfi, 1.0f / (sums[3] + EPS), ra * 0.8f, rd * 0.8f);
        P2[r] = make_float2(rm * 0.8f, Wbsurv[r] / fmaxf(sums[4], 1.0f));
    }
}

// ---------------- kernel 5: agent apply, float4 ----------------
__global__ __launch_bounds__(256) void k_apply(
    const int* __restrict__ reg, const float* __restrict__ greed,
    const float* __restrict__ atp, const float* __restrict__ adp,
    const float* __restrict__ amp,
    const float4* __restrict__ P4, const float2* __restrict__ P2,
    float* __restrict__ O)
{
    int q = blockIdx.x * 256 + threadIdx.x;
    if (q >= NAG / 4) return;
    int4 rr = ((const int4*)reg)[q];
    float4 g = ((const float4*)greed)[q];
    float4 a = ((const float4*)atp)[q];
    float4 d = ((const float4*)adp)[q];
    float4 m = ((const float4*)amp)[q];
    float4 oa, od, om;
#define ONE(c) { float4 t4 = P4[rr.c]; float2 t2 = P2[rr.c]; \
    float wn = (g.c + 1e-9f) * t4.y; \
    oa.c = a.c * t4.x + wn * t4.z + t2.y; \
    od.c = d.c * t4.x + wn * t4.w; \
    om.c = m.c * t4.x + wn * t2.x; }
    ONE(x) ONE(y) ONE(z) ONE(w)
#undef ONE
    ((float4*)(O + OUT_ATP))[q] = oa;
    ((float4*)(O + OUT_ADP))[q] = od;
    ((float4*)(O + OUT_AMP))[q] = om;
}

extern "C" void kernel_launch(void* const* d_in, const int* in_sizes, int n_in,
                              void* d_out, int out_size, void* d_ws, size_t ws_size,
                              hipStream_t stream) {
    const float* aec       = (const float*)d_in[0];
    const float* gdp_pc    = (const float*)d_in[1];
    const float* gdp_ema   = (const float*)d_in[2];
    const float* gdp_base  = (const float*)d_in[3];
    const float* dev_in    = (const float*)d_in[4];
    const float* sink_use  = (const float*)d_in[5];
    const float* sink_cap  = (const float*)d_in[6];
    const float* haz_base  = (const float*)d_in[7];
    const float* pop_age   = (const float*)d_in[8];
    const float* population= (const float*)d_in[9];
    const float* aging     = (const float*)d_in[10];
    const float* asfr      = (const float*)d_in[11];
    const float* distance  = (const float*)d_in[12];
    const float* cw        = (const float*)d_in[13];
    const float* pw        = (const float*)d_in[14];
    const float* cbase     = (const float*)d_in[15];
    const float* lbase     = (const float*)d_in[16];
    const float* greed     = (const float*)d_in[17];
    const float* eATP      = (const float*)d_in[18];
    const float* eADP      = (const float*)d_in[19];
    const float* eAMP      = (const float*)d_in[20];
    const float* patp      = (const float*)d_in[21];
    const float* padp      = (const float*)d_in[22];
    const float* pamp      = (const float*)d_in[23];
    const int*   nbr       = (const int*)d_in[24];
    const int*   reg       = (const int*)d_in[25];

    float* O = (float*)d_out;

    // -------- workspace layout (f32) --------
    float* W = (float*)d_ws;
    float* Wpa    = W;                       // RR*104 = 425984
    float* Wdfrac = Wpa    + RR * PAD_W;     // RR
    float* Wbsurv = Wdfrac + RR;
    float* Wattr  = Wbsurv + RR;
    float* Wgdist = Wattr  + RR;             // RR*32
    float* Wash   = Wgdist + RR * KK;        // RR*22
    float* Wmove  = Wash   + RR * 22;        // RR*32
    float* Wscal  = Wmove  + RR * KK;        // 4 (2 used)
    float* P4f    = Wscal  + 4;              // RR*4  (16B aligned offset)
    float* P2f    = P4f    + RR * 4;         // RR*2
    float* Wadd   = P2f    + RR * 2;         // RR*24
    float* T      = Wadd   + RR * 24;        // 5*CH*RR
    float* Smig   = T      + 5 * CH * RR;    // NCHUNK*22*RR
    float* S      = Smig   + (size_t)NCHUNK * 22 * RR;

    size_t fixed = (size_t)(S - W);
    int NB = 128;
    if ((fixed + (size_t)512 * 5 * RR) * 4 <= ws_size) NB = 512;
    else if ((fixed + (size_t)256 * 5 * RR) * 4 <= ws_size) NB = 256;

    k_zero<<<1, 64, 0, stream>>>(Wscal, 4);

    k_region1<<<RR / 4, 256, 0, stream>>>(
        aec, gdp_pc, gdp_ema, gdp_base, dev_in, sink_use, sink_cap, haz_base,
        pop_age, population, aging, asfr, distance, nbr,
        Wpa, Wdfrac, Wbsurv, Wattr, Wgdist, Wscal, O);

    k_migrate_a<<<RR / 4, 256, 0, stream>>>(nbr, Wattr, Wgdist, Wscal, Wpa, Wash, Wmove);

    k_migrate_b<<<NRANGE * NCHUNK, 256, 0, stream>>>(nbr, Wash, Wmove, Smig);

    if (NB == 512)      k_hist<512><<<512, 512, 0, stream>>>(reg, greed, eATP, eADP, eAMP, S);
    else if (NB == 256) k_hist<256><<<256, 512, 0, stream>>>(reg, greed, eATP, eADP, eAMP, S);
    else                k_hist<128><<<128, 512, 0, stream>>>(reg, greed, eATP, eADP, eAMP, S);

    k_reduce<<<640 + (22 * RR) / 256, 256, 0, stream>>>(S, Smig, T, Wadd, NB);

    k_fin<<<1024 + RR / 256, 256, 0, stream>>>(
        Wpa, Wadd, cw, pw, cbase, lbase, T, Wdfrac, Wbsurv,
        patp, padp, pamp, (float4*)P4f, (float2*)P2f, O);

    k_apply<<<(NAG / 4 + 255) / 256, 256, 0, stream>>>(
        reg, greed, eATP, eADP, eAMP, (const float4*)P4f, (const float2*)P2f, O);
}

// Round 6
// 118.678 us; speedup vs baseline: 11.5488x; 1.8755x over previous
//
#include <hip/hip_runtime.h>

#define RR 4096
#define AA 101
#define PAD_W 104
#define KK 32
#define NAG 4000000

#define NCHUNK 32
#define DR 512
#define NRANGE 8
#define EPB (RR * KK / NCHUNK)   // 4096 edges per chunk
#define CH 8

static constexpr float EPS  = 1e-9f;
static constexpr float DT   = 1.0f / 365.0f;
static constexpr float FRAC_MOVE = 0.02f / 365.0f;

static constexpr float SC13  = 8192.0f;          // 2^13
static constexpr float INV13 = 1.0f / 8192.0f;
static constexpr float SC20  = 1048576.0f;       // 2^20
static constexpr float INV20 = 1.0f / 1048576.0f;
static constexpr float SC18  = 262144.0f;        // 2^18
static constexpr float INV18 = 1.0f / 262144.0f;

// ---------------- d_out offsets (f32 elements, return order) ----------------
#define OUT_POP   0
#define OUT_POPN  413696
#define OUT_GDP   417792
#define OUT_DEV   421888
#define OUT_H     425984
#define OUT_CONS  430080
#define OUT_LAB   434176
#define OUT_PSR   438272
#define OUT_DEP   442368
#define OUT_ATP   446464
#define OUT_ADP   4446464
#define OUT_AMP   8446464
#define OUT_PATP  12446464
#define OUT_PADP  12450560
#define OUT_PAMP  12454656

static __device__ __forceinline__ float clampf(float x, float lo, float hi) {
    return fminf(fmaxf(x, lo), hi);
}
static __device__ __forceinline__ float wred(float x) {
#pragma unroll
    for (int m = 32; m; m >>= 1) x += __shfl_xor(x, m);
    return x;
}

// ---------------- kernel 1: per-region stage 1, wave-per-region ----------------
__global__ __launch_bounds__(256) void k_region1(
    const float* __restrict__ aec, const float* __restrict__ gdp_pc,
    const float* __restrict__ gdp_ema_in, const float* __restrict__ gdp_base,
    const float* __restrict__ dev_in, const float* __restrict__ sink_use,
    const float* __restrict__ sink_cap, const float* __restrict__ haz_base,
    const float* __restrict__ pop_age, const float* __restrict__ population,
    const float* __restrict__ aging, const float* __restrict__ asfr,
    const float* __restrict__ distance, const int* __restrict__ nbr,
    float* __restrict__ Wpa, float* __restrict__ Wdfrac, float* __restrict__ Wbsurv,
    float* __restrict__ Wattr, float* __restrict__ Wgdist, float* __restrict__ Wdsum,
    float* __restrict__ O)
{
    int wid = threadIdx.x >> 6, lane = threadIdx.x & 63;
    int r = blockIdx.x * 4 + wid;

    float aec_norm = clampf(aec[r], 0.0f, 1.0f);
    float gprev = gdp_ema_in[r];
    float gema  = gprev * 0.9f + 0.1f * gdp_pc[r];
    float base  = gdp_base[r];
    float g_ratio = logf(fmaxf(gema / (base + EPS), 1e-6f));
    float g_term  = clampf(0.5f + 0.5f * tanhf(0.5f * g_ratio), 0.0f, 1.0f);
    float util = clampf(sink_use[r] / (sink_cap[r] + EPS), 0.0f, 1.0f);
    float H = clampf(0.5f * aec_norm + 0.4f * g_term + 0.1f * (1.0f - util), 0.0f, 1.0f);
    float dev_proxy = clampf(0.5f + 0.5f * tanhf(0.3f * g_ratio), 0.0f, 1.0f);
    float dev = dev_in[r] * 0.99f + 0.01f * dev_proxy;

    float m_neon  = expf(-2.0f * H);
    float m_child = expf(-1.5f * H);
    float m_adult = expf(-1.0f * H);
    float hazmul = 1.0f + 0.5f * util;

    int a0 = lane * 2, a1 = a0 + 1;
    bool v0 = (a0 < AA), v1 = (a1 < AA);

    float p0 = 0.f, p1 = 0.f, hz0 = 0.f, hz1 = 0.f;
    if (v0) {
        p0 = pop_age[r * AA + a0];
        float mult = (a0 == 0) ? m_neon : ((a0 < 15) ? m_child : m_adult);
        hz0 = clampf(haz_base[a0] * mult * hazmul, 0.0f, 5.0f);
    }
    if (v1) {
        p1 = pop_age[r * AA + a1];
        float mult = (a1 < 15) ? m_child : m_adult;
        hz1 = clampf(haz_base[a1] * mult * hazmul, 0.0f, 5.0f);
    }
    float s0 = v0 ? p0 * expf(-hz0 * DT) : 0.f;
    float s1 = v1 ? p1 * expf(-hz1 * DT) : 0.f;
    float sp = __shfl_up(s1, 1);   // s[a0-1]

    float Md0 = 0.f, Md1 = 0.f, Ms0 = 0.f, Ms1 = 0.f;
    if (v0) { Md0 = aging[a0 * AA + a0]; if (a0 > 0) Ms0 = aging[(a0 - 1) * AA + a0]; }
    if (v1) { Md1 = aging[a1 * AA + a1]; Ms1 = aging[(a1 - 1) * AA + a1]; }

    float pa0 = v0 ? ((a0 == 0) ? s0 * Md0 : s0 * Md0 + sp * Ms0) : 0.f;
    float pa1 = v1 ? (s1 * Md1 + s0 * Ms1) : 0.f;

    if (v0 && a0 > 0) Wpa[r * PAD_W + a0] = pa0;
    if (v1)           Wpa[r * PAD_W + a1] = pa1;

    float pop_sum  = wred(p0 + p1);
    float surv_sum = wred(s0 + s1);
    float haz05 = wred(((v0 && a0 < 5) ? hz0 : 0.f) + ((v1 && a1 < 5) ? hz1 : 0.f));
    float bs0 = (a0 >= 15 && a0 < 50) ? 0.5f * pa0 * asfr[a0 - 15] : 0.f;
    float bs1 = (a1 >= 15 && a1 < 50) ? 0.5f * pa1 * asfr[a1 - 15] : 0.f;
    float b_sum = wred(bs0 + bs1);

    float dc = 0.f;
    if (lane < KK) {
        int idx = nbr[r * KK + lane];
        float d = distance[(size_t)r * RR + idx];
        Wgdist[r * KK + lane] = d;
        dc = d;
    }
    float dsum = wred(dc);

    if (lane == 0) {
        O[OUT_GDP + r] = gema;
        O[OUT_DEV + r] = dev;
        O[OUT_H + r]   = H;

        float deaths = fmaxf(pop_sum - surv_sum, 0.0f);
        Wdfrac[r] = clampf(deaths / (population[r] + EPS), 0.0f, 0.99f);

        float surv_u5 = expf(-haz05);
        float F_dev = clampf(expf(-dev), 0.5f, 1.5f);
        float F_rep = clampf(0.995f / fmaxf(surv_u5, 0.001f), 0.5f, 1.8f);
        float g_growth = logf(fmaxf(gema + EPS, 1e-6f)) - logf(fmaxf(gprev + EPS, 1e-6f));
        float F_cyc = clampf(expf(-5.0f * fmaxf(-g_growth, 0.0f)), 0.6f, 1.2f);
        float F_total = clampf(F_dev * F_rep * F_cyc, 0.4f, 1.8f);
        float births = fmaxf(b_sum * F_total * DT, 0.0f);
        float bsurv = births * expf(-hz0 * DT);       // hz0 on lane0 = haz[0]
        Wbsurv[r] = bsurv;
        Wpa[r * PAD_W + 0] = pa0 + bsurv;             // lane0 pa0 = pa(age 0)

        Wattr[r] = 0.6f * (gdp_pc[r] / (base + EPS)) + 0.4f * (0.5f + 0.5f * aec_norm);
        Wdsum[r] = dsum;
    }
}

// ---------------- kernel 1b: atomic-free global means ----------------
__global__ __launch_bounds__(1024) void k_means(
    const float* __restrict__ Wattr, const float* __restrict__ Wdsum,
    float* __restrict__ Wscal)
{
    __shared__ float sA[16], sD[16];
    int t = threadIdx.x;
    float a = Wattr[t] + Wattr[t + 1024] + Wattr[t + 2048] + Wattr[t + 3072];
    float d = Wdsum[t] + Wdsum[t + 1024] + Wdsum[t + 2048] + Wdsum[t + 3072];
    a = wred(a); d = wred(d);
    int wid = t >> 6, lane = t & 63;
    if (lane == 0) { sA[wid] = a; sD[wid] = d; }
    __syncthreads();
    if (t < 16) {
        float aa = sA[t], dd = sD[t];
#pragma unroll
        for (int m = 8; m; m >>= 1) { aa += __shfl_xor(aa, m); dd += __shfl_xor(dd, m); }
        if (t == 0) { Wscal[0] = aa; Wscal[1] = dd; }
    }
}

// ---------------- kernel 2a: migration weights + outflow, wave-per-region ----------------
__global__ __launch_bounds__(256) void k_migrate_a(
    const int* __restrict__ nbr, const float* __restrict__ Wattr,
    const float* __restrict__ Wgdist, const float* __restrict__ Wscal,
    float* __restrict__ Wpa, float* __restrict__ Wash, float* __restrict__ Wmove)
{
    int wid = threadIdx.x >> 6, lane = threadIdx.x & 63;
    int r = blockIdx.x * 4 + wid;

    float inv_am = 1.0f / (Wscal[0] / (float)RR + EPS);
    float inv_dm = 1.0f / (Wscal[1] / (float)(RR * KK) + EPS);

    float mob = 0.f;
    if (lane < 22) mob = Wpa[r * PAD_W + 18 + lane];
    float msum = wred(lane < 22 ? mob : 0.f);

    float w = 0.f;
    if (lane < KK) {
        int idx = nbr[r * KK + lane];
        float an = Wattr[idx] * inv_am;
        float cost = 1.0f + Wgdist[r * KK + lane] * inv_dm;
        w = fmaxf(an / cost, 0.0f);
    }
    float wsum = wred(lane < KK ? w : 0.f);

    float out_R = msum * FRAC_MOVE;
    float invw = 1.0f / (wsum + EPS);
    float move_sum = out_R * wsum * invw;
    float inv_ms = 1.0f / (msum + EPS);

    if (lane < 22) {
        float ash = mob * inv_ms;
        Wash[r * 22 + lane] = ash;
        Wpa[r * PAD_W + 18 + lane] = mob - ash * move_sum;
    }
    if (lane < KK) Wmove[r * KK + lane] = out_R * w * invw;
}

// ---------------- kernel 2b: inflow scatter, u64-packed LDS histograms ----------------
__global__ __launch_bounds__(256) void k_migrate_b(
    const int* __restrict__ nbr, const float* __restrict__ Wash,
    const float* __restrict__ Wmove, float* __restrict__ Smig)
{
    __shared__ unsigned long long h[11 * DR];   // 45056 B
    int range = blockIdx.x & (NRANGE - 1);
    int chunk = blockIdx.x >> 3;
    int d0 = range * DR;

    for (int i = threadIdx.x; i < 11 * DR; i += 256) h[i] = 0ull;
    __syncthreads();

    int tend = (chunk + 1) * EPB;
    for (int t = chunk * EPB + threadIdx.x; t < tend; t += 256) {
        int idx = nbr[t];
        if (idx >= d0 && idx < d0 + DR) {
            int rsrc = t >> 5;
            float mv = Wmove[t];
            const float* ash = &Wash[rsrc * 22];
            int dl = idx - d0;
#pragma unroll
            for (int f = 0; f < 11; f++) {
                unsigned long long lo = __float2uint_rn(ash[2 * f] * mv * SC18);
                unsigned long long hi = __float2uint_rn(ash[2 * f + 1] * mv * SC18);
                atomicAdd(&h[f * DR + dl], lo | (hi << 32));
            }
        }
    }
    __syncthreads();

    for (int i = threadIdx.x; i < 11 * DR; i += 256) {
        int f = i / DR, d = i - f * DR;
        unsigned long long v = h[i];
        Smig[(chunk * 22 + 2 * f) * RR + d0 + d]     = (float)(unsigned int)v * INV18;
        Smig[(chunk * 22 + 2 * f + 1) * RR + d0 + d] = (float)(v >> 32) * INV18;
    }
}

// ---------------- kernel 4: agent segment sums, 2 packed u64 atomics/agent ----------------
template<int NB>
__global__ __launch_bounds__(512) void k_hist(
    const int* __restrict__ reg, const float* __restrict__ greed,
    const float* __restrict__ atp, const float* __restrict__ adp,
    const float* __restrict__ amp, float* __restrict__ S)
{
    __shared__ unsigned long long hAB[RR];    // atp | adp<<32   (x2^13)
    __shared__ unsigned long long hMGC[RR];   // amp | greed<<28 | count<<56
    for (int i = threadIdx.x; i < RR; i += 512) { hAB[i] = 0ull; hMGC[i] = 0ull; }
    __syncthreads();

    const int4*   reg4 = (const int4*)reg;
    const float4* g4 = (const float4*)greed;
    const float4* a4 = (const float4*)atp;
    const float4* d4 = (const float4*)adp;
    const float4* m4 = (const float4*)amp;
    const int NQ = NAG / 4;

    for (int q = blockIdx.x * 512 + threadIdx.x; q < NQ; q += NB * 512) {
        int4 rr = reg4[q];
        float4 gv = g4[q], av = a4[q], dv = d4[q], mv = m4[q];
#define DO1(RX, GX, AX, DX, MX) { \
        unsigned long long ai = __float2uint_rn((AX) * SC13); \
        unsigned long long di = __float2uint_rn((DX) * SC13); \
        unsigned long long mi = __float2uint_rn((MX) * SC13); \
        unsigned long long gi = __float2uint_rn(((GX) + 1e-9f) * SC20); \
        atomicAdd(&hAB[RX],  ai | (di << 32)); \
        atomicAdd(&hMGC[RX], mi | (gi << 28) | (1ull << 56)); }
        DO1(rr.x, gv.x, av.x, dv.x, mv.x)
        DO1(rr.y, gv.y, av.y, dv.y, mv.y)
        DO1(rr.z, gv.z, av.z, dv.z, mv.z)
        DO1(rr.w, gv.w, av.w, dv.w, mv.w)
#undef DO1
    }
    __syncthreads();

    int b = blockIdx.x;
    for (int i = threadIdx.x; i < RR; i += 512) {
        unsigned long long ab = hAB[i], mgc = hMGC[i];
        S[((size_t)0 * NB + b) * RR + i] = (float)(unsigned int)ab * INV13;
        S[((size_t)1 * NB + b) * RR + i] = (float)(ab >> 32) * INV13;
        S[((size_t)2 * NB + b) * RR + i] = (float)(mgc & 0xFFFFFFFull) * INV13;
        S[((size_t)3 * NB + b) * RR + i] = (float)((mgc >> 28) & 0xFFFFFFFull) * INV20;
        S[((size_t)4 * NB + b) * RR + i] = (float)(mgc >> 56);
    }
}

// ---------------- kernel: reduce hist partials + fold Smig -> Wadd ----------------
__global__ __launch_bounds__(256) void k_reduce(
    const float* __restrict__ S, const float* __restrict__ Smig,
    float* __restrict__ T, float* __restrict__ Wadd, int NB)
{
    int blk = blockIdx.x;
    if (blk < 640) {
        int tid = blk * 256 + threadIdx.x;      // < 5*8*4096
        int r = tid & (RR - 1);
        int c = (tid >> 12) & (CH - 1);
        int s = tid >> 15;
        int bpc = NB >> 3;
        float acc = 0.f;
        for (int b = c * bpc; b < (c + 1) * bpc; b++)
            acc += S[((size_t)s * NB + b) * RR + r];
        T[(s * CH + c) * RR + r] = acc;
    } else {
        int t2 = (blk - 640) * 256 + threadIdx.x;   // < 22*4096
        int f = t2 >> 12, rr = t2 & (RR - 1);
        float acc = 0.f;
#pragma unroll
        for (int c = 0; c < NCHUNK; c++)
            acc += Smig[(c * 22 + f) * RR + rr];
        Wadd[rr * 24 + f] = acc;
    }
}

// ---------------- kernel: finalize population (wave/region) + region2 ----------------
__global__ __launch_bounds__(256) void k_fin(
    const float* __restrict__ Wpa, const float* __restrict__ Wadd,
    const float* __restrict__ cw, const float* __restrict__ pw,
    const float* __restrict__ cbase, const float* __restrict__ lbase,
    const float* __restrict__ T,
    const float* __restrict__ Wdfrac, const float* __restrict__ Wbsurv,
    const float* __restrict__ patp, const float* __restrict__ padp,
    const float* __restrict__ pamp,
    float4* __restrict__ P4, float2* __restrict__ P2,
    float* __restrict__ O)
{
    int blk = blockIdx.x;
    if (blk < 1024) {
        int wid = threadIdx.x >> 6, lane = threadIdx.x & 63;
        int r = blk * 4 + wid;
        int a0 = lane * 2, a1 = a0 + 1;
        bool v0 = (a0 < AA), v1 = (a1 < AA);

        float va = 0.f, vb = 0.f;
        if (lane < 51) {
            float2 pp = *(const float2*)&Wpa[r * PAD_W + a0];
            va = pp.x; vb = pp.y;
        }
        if (a0 >= 18 && a0 < 40) {
            float2 ad = *(const float2*)&Wadd[r * 24 + (a0 - 18)];
            va += ad.x; vb += ad.y;
        }
        va = v0 ? fmaxf(va, 0.0f) : 0.f;
        vb = v1 ? fmaxf(vb, 0.0f) : 0.f;
        if (v0) O[OUT_POP + r * AA + a0] = va;
        if (v1) O[OUT_POP + r * AA + a1] = vb;

        float cw0 = v0 ? cw[a0] : 0.f, cw1 = v1 ? cw[a1] : 0.f;
        float pw0 = v0 ? pw[a0] : 0.f, pw1 = v1 ? pw[a1] : 0.f;

        float psum  = wred(va + vb);
        float cdot  = wred(va * cw0 + vb * cw1);
        float ldot  = wred(va * pw0 + vb * pw1);
        float young = wred(((a0 < 15) ? va : 0.f) + ((a1 < 15) ? vb : 0.f));
        float work  = wred(((a0 >= 15 && a0 < 65) ? va : 0.f) + ((a1 >= 15 && a1 < 65) ? vb : 0.f));
        float old   = wred(((a0 >= 65) ? va : 0.f) + ((a1 >= 65) ? vb : 0.f));

        if (lane == 0) {
            O[OUT_POPN + r] = fmaxf(psum, 0.0f);
            O[OUT_CONS + r] = clampf(cdot / (cbase[r] + EPS), 0.25f, 4.0f);
            O[OUT_LAB + r]  = clampf(ldot / (lbase[r] + EPS), 0.2f, 1.2f);
            O[OUT_PSR + r]  = work / (old + EPS);
            O[OUT_DEP + r]  = (young + old) / (work + EPS);
        }
    } else {
        int r = (blk - 1024) * 256 + threadIdx.x;
        if (r >= RR) return;
        float sums[5];
#pragma unroll
        for (int s = 0; s < 5; s++) {
            float acc = 0.f;
#pragma unroll
            for (int c = 0; c < CH; c++)
                acc += T[(s * CH + c) * RR + r];
            sums[s] = acc;
        }
        float dfi = Wdfrac[r];
        float ra = sums[0] * dfi;
        float rd = sums[1] * dfi;
        float rm = sums[2] * dfi;
        O[OUT_PATP + r] = patp[r] - ra * 0.2f;
        O[OUT_PADP + r] = padp[r] - rd * 0.2f;
        O[OUT_PAMP + r] = pamp[r] - rm * 0.2f;
        P4[r] = make_float4(1.0f - dfi, 1.0f / (sums[3] + EPS), ra * 0.8f, rd * 0.8f);
        P2[r] = make_float2(rm * 0.8f, Wbsurv[r] / fmaxf(sums[4], 1.0f));
    }
}

// ---------------- kernel 5: agent apply, float4 ----------------
__global__ __launch_bounds__(256) void k_apply(
    const int* __restrict__ reg, const float* __restrict__ greed,
    const float* __restrict__ atp, const float* __restrict__ adp,
    const float* __restrict__ amp,
    const float4* __restrict__ P4, const float2* __restrict__ P2,
    float* __restrict__ O)
{
    int q = blockIdx.x * 256 + threadIdx.x;
    if (q >= NAG / 4) return;
    int4 rr = ((const int4*)reg)[q];
    float4 g = ((const float4*)greed)[q];
    float4 a = ((const float4*)atp)[q];
    float4 d = ((const float4*)adp)[q];
    float4 m = ((const float4*)amp)[q];
    float4 oa, od, om;
#define ONE(c) { float4 t4 = P4[rr.c]; float2 t2 = P2[rr.c]; \
    float wn = (g.c + 1e-9f) * t4.y; \
    oa.c = a.c * t4.x + wn * t4.z + t2.y; \
    od.c = d.c * t4.x + wn * t4.w; \
    om.c = m.c * t4.x + wn * t2.x; }
    ONE(x) ONE(y) ONE(z) ONE(w)
#undef ONE
    ((float4*)(O + OUT_ATP))[q] = oa;
    ((float4*)(O + OUT_ADP))[q] = od;
    ((float4*)(O + OUT_AMP))[q] = om;
}

extern "C" void kernel_launch(void* const* d_in, const int* in_sizes, int n_in,
                              void* d_out, int out_size, void* d_ws, size_t ws_size,
                              hipStream_t stream) {
    const float* aec       = (const float*)d_in[0];
    const float* gdp_pc    = (const float*)d_in[1];
    const float* gdp_ema   = (const float*)d_in[2];
    const float* gdp_base  = (const float*)d_in[3];
    const float* dev_in    = (const float*)d_in[4];
    const float* sink_use  = (const float*)d_in[5];
    const float* sink_cap  = (const float*)d_in[6];
    const float* haz_base  = (const float*)d_in[7];
    const float* pop_age   = (const float*)d_in[8];
    const float* population= (const float*)d_in[9];
    const float* aging     = (const float*)d_in[10];
    const float* asfr      = (const float*)d_in[11];
    const float* distance  = (const float*)d_in[12];
    const float* cw        = (const float*)d_in[13];
    const float* pw        = (const float*)d_in[14];
    const float* cbase     = (const float*)d_in[15];
    const float* lbase     = (const float*)d_in[16];
    const float* greed     = (const float*)d_in[17];
    const float* eATP      = (const float*)d_in[18];
    const float* eADP      = (const float*)d_in[19];
    const float* eAMP      = (const float*)d_in[20];
    const float* patp      = (const float*)d_in[21];
    const float* padp      = (const float*)d_in[22];
    const float* pamp      = (const float*)d_in[23];
    const int*   nbr       = (const int*)d_in[24];
    const int*   reg       = (const int*)d_in[25];

    float* O = (float*)d_out;

    // -------- workspace layout (f32) --------
    float* W = (float*)d_ws;
    float* Wpa    = W;                       // RR*104
    float* Wdfrac = Wpa    + RR * PAD_W;
    float* Wbsurv = Wdfrac + RR;
    float* Wattr  = Wbsurv + RR;
    float* Wgdist = Wattr  + RR;             // RR*32
    float* Wash   = Wgdist + RR * KK;        // RR*22
    float* Wmove  = Wash   + RR * 22;        // RR*32
    float* Wdsum  = Wmove  + RR * KK;        // RR
    float* Wscal  = Wdsum  + RR;             // 4 (2 used)
    float* P4f    = Wscal  + 4;              // RR*4  (16B aligned offset)
    float* P2f    = P4f    + RR * 4;         // RR*2
    float* Wadd   = P2f    + RR * 2;         // RR*24
    float* T      = Wadd   + RR * 24;        // 5*CH*RR
    float* Smig   = T      + 5 * CH * RR;    // NCHUNK*22*RR
    float* S      = Smig   + (size_t)NCHUNK * 22 * RR;

    size_t fixed = (size_t)(S - W);
    int NB = 128;
    if ((fixed + (size_t)512 * 5 * RR) * 4 <= ws_size) NB = 512;
    else if ((fixed + (size_t)256 * 5 * RR) * 4 <= ws_size) NB = 256;

    k_region1<<<RR / 4, 256, 0, stream>>>(
        aec, gdp_pc, gdp_ema, gdp_base, dev_in, sink_use, sink_cap, haz_base,
        pop_age, population, aging, asfr, distance, nbr,
        Wpa, Wdfrac, Wbsurv, Wattr, Wgdist, Wdsum, O);

    k_means<<<1, 1024, 0, stream>>>(Wattr, Wdsum, Wscal);

    k_migrate_a<<<RR / 4, 256, 0, stream>>>(nbr, Wattr, Wgdist, Wscal, Wpa, Wash, Wmove);

    k_migrate_b<<<NRANGE * NCHUNK, 256, 0, stream>>>(nbr, Wash, Wmove, Smig);

    if (NB == 512)      k_hist<512><<<512, 512, 0, stream>>>(reg, greed, eATP, eADP, eAMP, S);
    else if (NB == 256) k_hist<256><<<256, 512, 0, stream>>>(reg, greed, eATP, eADP, eAMP, S);
    else                k_hist<128><<<128, 512, 0, stream>>>(reg, greed, eATP, eADP, eAMP, S);

    k_reduce<<<640 + (22 * RR) / 256, 256, 0, stream>>>(S, Smig, T, Wadd, NB);

    k_fin<<<1024 + RR / 256, 256, 0, stream>>>(
        Wpa, Wadd, cw, pw, cbase, lbase, T, Wdfrac, Wbsurv,
        patp, padp, pamp, (float4*)P4f, (float2*)P2f, O);

    k_apply<<<(NAG / 4 + 255) / 256, 256, 0, stream>>>(
        reg, greed, eATP, eADP, eAMP, (const float4*)P4f, (const float2*)P2f, O);
}

// Round 7
// 107.681 us; speedup vs baseline: 12.7282x; 1.1021x over previous
//
#include <hip/hip_runtime.h>

#define RR 4096
#define AA 101
#define PAD_W 104
#define KK 32
#define NAG 4000000

#define NCHUNK 32
#define DR 512
#define NRANGE 8
#define EPB (RR * KK / NCHUNK)   // 4096 edges per chunk
#define CH 8
#define NB 512                   // hist blocks

static constexpr float EPS  = 1e-9f;
static constexpr float DT   = 1.0f / 365.0f;
static constexpr float FRAC_MOVE = 0.02f / 365.0f;

static constexpr float SC13  = 8192.0f;          // 2^13
static constexpr float INV13 = 1.0f / 8192.0f;
static constexpr float SC20  = 1048576.0f;       // 2^20
static constexpr float INV20 = 1.0f / 1048576.0f;
static constexpr float SC18  = 262144.0f;        // 2^18
static constexpr float INV18 = 1.0f / 262144.0f;

// ---------------- d_out offsets (f32 elements, return order) ----------------
#define OUT_POP   0
#define OUT_POPN  413696
#define OUT_GDP   417792
#define OUT_DEV   421888
#define OUT_H     425984
#define OUT_CONS  430080
#define OUT_LAB   434176
#define OUT_PSR   438272
#define OUT_DEP   442368
#define OUT_ATP   446464
#define OUT_ADP   4446464
#define OUT_AMP   8446464
#define OUT_PATP  12446464
#define OUT_PADP  12450560
#define OUT_PAMP  12454656

static __device__ __forceinline__ float clampf(float x, float lo, float hi) {
    return fminf(fmaxf(x, lo), hi);
}
static __device__ __forceinline__ float wred(float x) {
#pragma unroll
    for (int m = 32; m; m >>= 1) x += __shfl_xor(x, m);
    return x;
}

// ---------------- kernel 1: per-region stage 1, wave-per-region ----------------
__global__ __launch_bounds__(256) void k_region1(
    const float* __restrict__ aec, const float* __restrict__ gdp_pc,
    const float* __restrict__ gdp_ema_in, const float* __restrict__ gdp_base,
    const float* __restrict__ dev_in, const float* __restrict__ sink_use,
    const float* __restrict__ sink_cap, const float* __restrict__ haz_base,
    const float* __restrict__ pop_age, const float* __restrict__ population,
    const float* __restrict__ aging, const float* __restrict__ asfr,
    const float* __restrict__ distance, const int* __restrict__ nbr,
    float* __restrict__ Wpa, float* __restrict__ Wdfrac, float* __restrict__ Wbsurv,
    float* __restrict__ Wattr, float* __restrict__ Wgdist, float* __restrict__ Wdsum,
    float* __restrict__ O)
{
    int wid = threadIdx.x >> 6, lane = threadIdx.x & 63;
    int r = blockIdx.x * 4 + wid;

    float aec_norm = clampf(aec[r], 0.0f, 1.0f);
    float gprev = gdp_ema_in[r];
    float gema  = gprev * 0.9f + 0.1f * gdp_pc[r];
    float base  = gdp_base[r];
    float g_ratio = logf(fmaxf(gema / (base + EPS), 1e-6f));
    float g_term  = clampf(0.5f + 0.5f * tanhf(0.5f * g_ratio), 0.0f, 1.0f);
    float util = clampf(sink_use[r] / (sink_cap[r] + EPS), 0.0f, 1.0f);
    float H = clampf(0.5f * aec_norm + 0.4f * g_term + 0.1f * (1.0f - util), 0.0f, 1.0f);
    float dev_proxy = clampf(0.5f + 0.5f * tanhf(0.3f * g_ratio), 0.0f, 1.0f);
    float dev = dev_in[r] * 0.99f + 0.01f * dev_proxy;

    float m_neon  = expf(-2.0f * H);
    float m_child = expf(-1.5f * H);
    float m_adult = expf(-1.0f * H);
    float hazmul = 1.0f + 0.5f * util;

    int a0 = lane * 2, a1 = a0 + 1;
    bool v0 = (a0 < AA), v1 = (a1 < AA);

    float p0 = 0.f, p1 = 0.f, hz0 = 0.f, hz1 = 0.f;
    if (v0) {
        p0 = pop_age[r * AA + a0];
        float mult = (a0 == 0) ? m_neon : ((a0 < 15) ? m_child : m_adult);
        hz0 = clampf(haz_base[a0] * mult * hazmul, 0.0f, 5.0f);
    }
    if (v1) {
        p1 = pop_age[r * AA + a1];
        float mult = (a1 < 15) ? m_child : m_adult;
        hz1 = clampf(haz_base[a1] * mult * hazmul, 0.0f, 5.0f);
    }
    float s0 = v0 ? p0 * expf(-hz0 * DT) : 0.f;
    float s1 = v1 ? p1 * expf(-hz1 * DT) : 0.f;
    float sp = __shfl_up(s1, 1);   // s[a0-1]

    float Md0 = 0.f, Md1 = 0.f, Ms0 = 0.f, Ms1 = 0.f;
    if (v0) { Md0 = aging[a0 * AA + a0]; if (a0 > 0) Ms0 = aging[(a0 - 1) * AA + a0]; }
    if (v1) { Md1 = aging[a1 * AA + a1]; Ms1 = aging[(a1 - 1) * AA + a1]; }

    float pa0 = v0 ? ((a0 == 0) ? s0 * Md0 : s0 * Md0 + sp * Ms0) : 0.f;
    float pa1 = v1 ? (s1 * Md1 + s0 * Ms1) : 0.f;

    if (v0 && a0 > 0) Wpa[r * PAD_W + a0] = pa0;
    if (v1)           Wpa[r * PAD_W + a1] = pa1;

    float pop_sum  = wred(p0 + p1);
    float surv_sum = wred(s0 + s1);
    float haz05 = wred(((v0 && a0 < 5) ? hz0 : 0.f) + ((v1 && a1 < 5) ? hz1 : 0.f));
    float bs0 = (a0 >= 15 && a0 < 50) ? 0.5f * pa0 * asfr[a0 - 15] : 0.f;
    float bs1 = (a1 >= 15 && a1 < 50) ? 0.5f * pa1 * asfr[a1 - 15] : 0.f;
    float b_sum = wred(bs0 + bs1);

    float dc = 0.f;
    if (lane < KK) {
        int idx = nbr[r * KK + lane];
        float d = distance[(size_t)r * RR + idx];
        Wgdist[r * KK + lane] = d;
        dc = d;
    }
    float dsum = wred(dc);

    if (lane == 0) {
        O[OUT_GDP + r] = gema;
        O[OUT_DEV + r] = dev;
        O[OUT_H + r]   = H;

        float deaths = fmaxf(pop_sum - surv_sum, 0.0f);
        Wdfrac[r] = clampf(deaths / (population[r] + EPS), 0.0f, 0.99f);

        float surv_u5 = expf(-haz05);
        float F_dev = clampf(expf(-dev), 0.5f, 1.5f);
        float F_rep = clampf(0.995f / fmaxf(surv_u5, 0.001f), 0.5f, 1.8f);
        float g_growth = logf(fmaxf(gema + EPS, 1e-6f)) - logf(fmaxf(gprev + EPS, 1e-6f));
        float F_cyc = clampf(expf(-5.0f * fmaxf(-g_growth, 0.0f)), 0.6f, 1.2f);
        float F_total = clampf(F_dev * F_rep * F_cyc, 0.4f, 1.8f);
        float births = fmaxf(b_sum * F_total * DT, 0.0f);
        float bsurv = births * expf(-hz0 * DT);       // hz0 on lane0 = haz[0]
        Wbsurv[r] = bsurv;
        Wpa[r * PAD_W + 0] = pa0 + bsurv;             // lane0 pa0 = pa(age 0)

        Wattr[r] = 0.6f * (gdp_pc[r] / (base + EPS)) + 0.4f * (0.5f + 0.5f * aec_norm);
        Wdsum[r] = dsum;
    }
}

// ---------------- kernel 2a: migration weights + outflow (means inlined) ----------------
__global__ __launch_bounds__(256) void k_migrate_a(
    const int* __restrict__ nbr, const float* __restrict__ Wattr,
    const float* __restrict__ Wgdist, const float* __restrict__ Wdsum,
    float* __restrict__ Wpa, float* __restrict__ Wash, float* __restrict__ Wmove)
{
    __shared__ float sred[8];
    int t = threadIdx.x;
    {
        float a = 0.f, d = 0.f;
        for (int i = t; i < RR; i += 256) { a += Wattr[i]; d += Wdsum[i]; }
        a = wred(a); d = wred(d);
        int w0 = t >> 6;
        if ((t & 63) == 0) { sred[w0] = a; sred[4 + w0] = d; }
    }
    __syncthreads();
    float asum = sred[0] + sred[1] + sred[2] + sred[3];
    float dall = sred[4] + sred[5] + sred[6] + sred[7];
    float inv_am = 1.0f / (asum / (float)RR + EPS);
    float inv_dm = 1.0f / (dall / (float)(RR * KK) + EPS);

    int wid = t >> 6, lane = t & 63;
    int r = blockIdx.x * 4 + wid;

    float mob = 0.f;
    if (lane < 22) mob = Wpa[r * PAD_W + 18 + lane];
    float msum = wred(lane < 22 ? mob : 0.f);

    float w = 0.f;
    if (lane < KK) {
        int idx = nbr[r * KK + lane];
        float an = Wattr[idx] * inv_am;
        float cost = 1.0f + Wgdist[r * KK + lane] * inv_dm;
        w = fmaxf(an / cost, 0.0f);
    }
    float wsum = wred(lane < KK ? w : 0.f);

    float out_R = msum * FRAC_MOVE;
    float invw = 1.0f / (wsum + EPS);
    float move_sum = out_R * wsum * invw;
    float inv_ms = 1.0f / (msum + EPS);

    if (lane < 22) {
        float ash = mob * inv_ms;
        Wash[r * 22 + lane] = ash;
        Wpa[r * PAD_W + 18 + lane] = mob - ash * move_sum;
    }
    if (lane < KK) Wmove[r * KK + lane] = out_R * w * invw;
}

// ---------------- kernel 2b: inflow scatter, u64-packed LDS histograms ----------------
__global__ __launch_bounds__(256) void k_migrate_b(
    const int* __restrict__ nbr, const float* __restrict__ Wash,
    const float* __restrict__ Wmove, float* __restrict__ Smig)
{
    __shared__ unsigned long long h[11 * DR];   // 45056 B
    int range = blockIdx.x & (NRANGE - 1);
    int chunk = blockIdx.x >> 3;
    int d0 = range * DR;

    for (int i = threadIdx.x; i < 11 * DR; i += 256) h[i] = 0ull;
    __syncthreads();

    int tend = (chunk + 1) * EPB;
    for (int t = chunk * EPB + threadIdx.x; t < tend; t += 256) {
        int idx = nbr[t];
        if (idx >= d0 && idx < d0 + DR) {
            int rsrc = t >> 5;
            float mv = Wmove[t];
            const float* ash = &Wash[rsrc * 22];
            int dl = idx - d0;
#pragma unroll
            for (int f = 0; f < 11; f++) {
                unsigned long long lo = __float2uint_rn(ash[2 * f] * mv * SC18);
                unsigned long long hi = __float2uint_rn(ash[2 * f + 1] * mv * SC18);
                atomicAdd(&h[f * DR + dl], lo | (hi << 32));
            }
        }
    }
    __syncthreads();

    for (int i = threadIdx.x; i < 11 * DR; i += 256) {
        int f = i / DR, d = i - f * DR;
        unsigned long long v = h[i];
        Smig[(chunk * 22 + 2 * f) * RR + d0 + d]     = (float)(unsigned int)v * INV18;
        Smig[(chunk * 22 + 2 * f + 1) * RR + d0 + d] = (float)(v >> 32) * INV18;
    }
}

// ---------------- kernel 4: agent segment sums, deep-MLP one-shot ----------------
__global__ __launch_bounds__(512, 4) void k_hist(
    const int* __restrict__ reg, const float* __restrict__ greed,
    const float* __restrict__ atp, const float* __restrict__ adp,
    const float* __restrict__ amp, float* __restrict__ S)
{
    __shared__ unsigned long long hAB[RR];    // atp | adp<<32   (x2^13)
    __shared__ unsigned long long hMGC[RR];   // amp | greed<<28 | count<<56
    for (int i = threadIdx.x; i < RR; i += 512) { hAB[i] = 0ull; hMGC[i] = 0ull; }
    __syncthreads();

    const int4*   reg4 = (const int4*)reg;
    const float4* g4 = (const float4*)greed;
    const float4* a4 = (const float4*)atp;
    const float4* d4 = (const float4*)adp;
    const float4* m4 = (const float4*)amp;
    const int NQ = NAG / 4;
    const int STRIDE = NB * 512;

    int q0 = blockIdx.x * 512 + threadIdx.x;
    int4 rrv[4]; float4 gv[4], av[4], dv[4], mv[4];
    bool ok[4];
#pragma unroll
    for (int c = 0; c < 4; c++) {
        int q = q0 + c * STRIDE;
        ok[c] = (q < NQ);
        int qq = ok[c] ? q : 0;
        rrv[c] = reg4[qq];
        gv[c] = g4[qq];
        av[c] = a4[qq];
        dv[c] = d4[qq];
        mv[c] = m4[qq];
    }

#pragma unroll
    for (int c = 0; c < 4; c++) {
        if (!ok[c]) continue;
#define DO1(RX, GX, AX, DX, MX) { \
        unsigned long long ai = __float2uint_rn((AX) * SC13); \
        unsigned long long di = __float2uint_rn((DX) * SC13); \
        unsigned long long mi = __float2uint_rn((MX) * SC13); \
        unsigned long long gi = __float2uint_rn(((GX) + 1e-9f) * SC20); \
        atomicAdd(&hAB[RX],  ai | (di << 32)); \
        atomicAdd(&hMGC[RX], mi | (gi << 28) | (1ull << 56)); }
        DO1(rrv[c].x, gv[c].x, av[c].x, dv[c].x, mv[c].x)
        DO1(rrv[c].y, gv[c].y, av[c].y, dv[c].y, mv[c].y)
        DO1(rrv[c].z, gv[c].z, av[c].z, dv[c].z, mv[c].z)
        DO1(rrv[c].w, gv[c].w, av[c].w, dv[c].w, mv[c].w)
#undef DO1
    }
    __syncthreads();

    int b = blockIdx.x;
    for (int i = threadIdx.x; i < RR; i += 512) {
        unsigned long long ab = hAB[i], mgc = hMGC[i];
        S[((size_t)0 * NB + b) * RR + i] = (float)(unsigned int)ab * INV13;
        S[((size_t)1 * NB + b) * RR + i] = (float)(ab >> 32) * INV13;
        S[((size_t)2 * NB + b) * RR + i] = (float)(mgc & 0xFFFFFFFull) * INV13;
        S[((size_t)3 * NB + b) * RR + i] = (float)((mgc >> 28) & 0xFFFFFFFull) * INV20;
        S[((size_t)4 * NB + b) * RR + i] = (float)(mgc >> 56);
    }
}

// ---------------- kernel: reduce hist partials + fold Smig -> Wadd ----------------
__global__ __launch_bounds__(256) void k_reduce(
    const float* __restrict__ S, const float* __restrict__ Smig,
    float* __restrict__ T, float* __restrict__ Wadd)
{
    int blk = blockIdx.x;
    if (blk < 640) {
        int tid = blk * 256 + threadIdx.x;      // < 5*8*4096
        int r = tid & (RR - 1);
        int c = (tid >> 12) & (CH - 1);
        int s = tid >> 15;
        int bpc = NB >> 3;
        float acc = 0.f;
        for (int b = c * bpc; b < (c + 1) * bpc; b++)
            acc += S[((size_t)s * NB + b) * RR + r];
        T[(s * CH + c) * RR + r] = acc;
    } else {
        int t2 = (blk - 640) * 256 + threadIdx.x;   // < 22*4096
        int f = t2 >> 12, rr = t2 & (RR - 1);
        float acc = 0.f;
#pragma unroll
        for (int c = 0; c < NCHUNK; c++)
            acc += Smig[(c * 22 + f) * RR + rr];
        Wadd[rr * 24 + f] = acc;
    }
}

// ---------------- kernel: finalize population (wave/region) + region2 ----------------
__global__ __launch_bounds__(256) void k_fin(
    const float* __restrict__ Wpa, const float* __restrict__ Wadd,
    const float* __restrict__ cw, const float* __restrict__ pw,
    const float* __restrict__ cbase, const float* __restrict__ lbase,
    const float* __restrict__ T,
    const float* __restrict__ Wdfrac, const float* __restrict__ Wbsurv,
    const float* __restrict__ patp, const float* __restrict__ padp,
    const float* __restrict__ pamp,
    float4* __restrict__ P4, float2* __restrict__ P2,
    float* __restrict__ O)
{
    int blk = blockIdx.x;
    if (blk < 1024) {
        int wid = threadIdx.x >> 6, lane = threadIdx.x & 63;
        int r = blk * 4 + wid;
        int a0 = lane * 2, a1 = a0 + 1;
        bool v0 = (a0 < AA), v1 = (a1 < AA);

        float va = 0.f, vb = 0.f;
        if (lane < 51) {
            float2 pp = *(const float2*)&Wpa[r * PAD_W + a0];
            va = pp.x; vb = pp.y;
        }
        if (a0 >= 18 && a0 < 40) {
            float2 ad = *(const float2*)&Wadd[r * 24 + (a0 - 18)];
            va += ad.x; vb += ad.y;
        }
        va = v0 ? fmaxf(va, 0.0f) : 0.f;
        vb = v1 ? fmaxf(vb, 0.0f) : 0.f;
        if (v0) O[OUT_POP + r * AA + a0] = va;
        if (v1) O[OUT_POP + r * AA + a1] = vb;

        float cw0 = v0 ? cw[a0] : 0.f, cw1 = v1 ? cw[a1] : 0.f;
        float pw0 = v0 ? pw[a0] : 0.f, pw1 = v1 ? pw[a1] : 0.f;

        float psum  = wred(va + vb);
        float cdot  = wred(va * cw0 + vb * cw1);
        float ldot  = wred(va * pw0 + vb * pw1);
        float young = wred(((a0 < 15) ? va : 0.f) + ((a1 < 15) ? vb : 0.f));
        float work  = wred(((a0 >= 15 && a0 < 65) ? va : 0.f) + ((a1 >= 15 && a1 < 65) ? vb : 0.f));
        float old   = wred(((a0 >= 65) ? va : 0.f) + ((a1 >= 65) ? vb : 0.f));

        if (lane == 0) {
            O[OUT_POPN + r] = fmaxf(psum, 0.0f);
            O[OUT_CONS + r] = clampf(cdot / (cbase[r] + EPS), 0.25f, 4.0f);
            O[OUT_LAB + r]  = clampf(ldot / (lbase[r] + EPS), 0.2f, 1.2f);
            O[OUT_PSR + r]  = work / (old + EPS);
            O[OUT_DEP + r]  = (young + old) / (work + EPS);
        }
    } else {
        int r = (blk - 1024) * 256 + threadIdx.x;
        if (r >= RR) return;
        float sums[5];
#pragma unroll
        for (int s = 0; s < 5; s++) {
            float acc = 0.f;
#pragma unroll
            for (int c = 0; c < CH; c++)
                acc += T[(s * CH + c) * RR + r];
            sums[s] = acc;
        }
        float dfi = Wdfrac[r];
        float ra = sums[0] * dfi;
        float rd = sums[1] * dfi;
        float rm = sums[2] * dfi;
        O[OUT_PATP + r] = patp[r] - ra * 0.2f;
        O[OUT_PADP + r] = padp[r] - rd * 0.2f;
        O[OUT_PAMP + r] = pamp[r] - rm * 0.2f;
        P4[r] = make_float4(1.0f - dfi, 1.0f / (sums[3] + EPS), ra * 0.8f, rd * 0.8f);
        P2[r] = make_float2(rm * 0.8f, Wbsurv[r] / fmaxf(sums[4], 1.0f));
    }
}

// ---------------- kernel 5: agent apply, float4 ----------------
__global__ __launch_bounds__(256) void k_apply(
    const int* __restrict__ reg, const float* __restrict__ greed,
    const float* __restrict__ atp, const float* __restrict__ adp,
    const float* __restrict__ amp,
    const float4* __restrict__ P4, const float2* __restrict__ P2,
    float* __restrict__ O)
{
    int q = blockIdx.x * 256 + threadIdx.x;
    if (q >= NAG / 4) return;
    int4 rr = ((const int4*)reg)[q];
    float4 g = ((const float4*)greed)[q];
    float4 a = ((const float4*)atp)[q];
    float4 d = ((const float4*)adp)[q];
    float4 m = ((const float4*)amp)[q];
    float4 oa, od, om;
#define ONE(c) { float4 t4 = P4[rr.c]; float2 t2 = P2[rr.c]; \
    float wn = (g.c + 1e-9f) * t4.y; \
    oa.c = a.c * t4.x + wn * t4.z + t2.y; \
    od.c = d.c * t4.x + wn * t4.w; \
    om.c = m.c * t4.x + wn * t2.x; }
    ONE(x) ONE(y) ONE(z) ONE(w)
#undef ONE
    ((float4*)(O + OUT_ATP))[q] = oa;
    ((float4*)(O + OUT_ADP))[q] = od;
    ((float4*)(O + OUT_AMP))[q] = om;
}

extern "C" void kernel_launch(void* const* d_in, const int* in_sizes, int n_in,
                              void* d_out, int out_size, void* d_ws, size_t ws_size,
                              hipStream_t stream) {
    const float* aec       = (const float*)d_in[0];
    const float* gdp_pc    = (const float*)d_in[1];
    const float* gdp_ema   = (const float*)d_in[2];
    const float* gdp_base  = (const float*)d_in[3];
    const float* dev_in    = (const float*)d_in[4];
    const float* sink_use  = (const float*)d_in[5];
    const float* sink_cap  = (const float*)d_in[6];
    const float* haz_base  = (const float*)d_in[7];
    const float* pop_age   = (const float*)d_in[8];
    const float* population= (const float*)d_in[9];
    const float* aging     = (const float*)d_in[10];
    const float* asfr      = (const float*)d_in[11];
    const float* distance  = (const float*)d_in[12];
    const float* cw        = (const float*)d_in[13];
    const float* pw        = (const float*)d_in[14];
    const float* cbase     = (const float*)d_in[15];
    const float* lbase     = (const float*)d_in[16];
    const float* greed     = (const float*)d_in[17];
    const float* eATP      = (const float*)d_in[18];
    const float* eADP      = (const float*)d_in[19];
    const float* eAMP      = (const float*)d_in[20];
    const float* patp      = (const float*)d_in[21];
    const float* padp      = (const float*)d_in[22];
    const float* pamp      = (const float*)d_in[23];
    const int*   nbr       = (const int*)d_in[24];
    const int*   reg       = (const int*)d_in[25];

    float* O = (float*)d_out;

    // -------- workspace layout (f32), all blocks RR-multiples (16KB aligned) --------
    float* W = (float*)d_ws;
    float* Wpa    = W;                       // RR*104
    float* Wdfrac = Wpa    + RR * PAD_W;
    float* Wbsurv = Wdfrac + RR;
    float* Wattr  = Wbsurv + RR;
    float* Wdsum  = Wattr  + RR;
    float* Wgdist = Wdsum  + RR;             // RR*32
    float* Wash   = Wgdist + RR * KK;        // RR*22
    float* Wmove  = Wash   + RR * 22;        // RR*32
    float* P4f    = Wmove  + RR * KK;        // RR*4
    float* P2f    = P4f    + RR * 4;         // RR*2
    float* Wadd   = P2f    + RR * 2;         // RR*24
    float* T      = Wadd   + RR * 24;        // 5*CH*RR
    float* Smig   = T      + 5 * CH * RR;    // NCHUNK*22*RR
    float* S      = Smig   + (size_t)NCHUNK * 22 * RR;   // NB*5*RR

    k_region1<<<RR / 4, 256, 0, stream>>>(
        aec, gdp_pc, gdp_ema, gdp_base, dev_in, sink_use, sink_cap, haz_base,
        pop_age, population, aging, asfr, distance, nbr,
        Wpa, Wdfrac, Wbsurv, Wattr, Wgdist, Wdsum, O);

    k_migrate_a<<<RR / 4, 256, 0, stream>>>(nbr, Wattr, Wgdist, Wdsum, Wpa, Wash, Wmove);

    k_migrate_b<<<NRANGE * NCHUNK, 256, 0, stream>>>(nbr, Wash, Wmove, Smig);

    k_hist<<<NB, 512, 0, stream>>>(reg, greed, eATP, eADP, eAMP, S);

    k_reduce<<<640 + (22 * RR) / 256, 256, 0, stream>>>(S, Smig, T, Wadd);

    k_fin<<<1024 + RR / 256, 256, 0, stream>>>(
        Wpa, Wadd, cw, pw, cbase, lbase, T, Wdfrac, Wbsurv,
        patp, padp, pamp, (float4*)P4f, (float2*)P2f, O);

    k_apply<<<(NAG / 4 + 255) / 256, 256, 0, stream>>>(
        reg, greed, eATP, eADP, eAMP, (const float4*)P4f, (const float2*)P2f, O);
}